// Round 2
// baseline (7913.827 us; speedup 1.0000x reference)
//
#include <hip/hip_runtime.h>
#include <cstdint>
#include <cstddef>
#include <cmath>

// ---------------------------------------------------------------------------
// Pipeline:
//   A  k_chain  : exact sequential float32 cumsums (row-major out), 8 blocks,
//                 global_load_lds ring + counted vmcnt (never 0 in main loop)
//   B  k_diffs  : exact numpy-pairwise variance->diffs per position
//   C  k_hist1/k_sel_hi/k_hist2/k_sel_lo : exact top-32768 radix select
//   D  k_keep   : keep flags, stable tie ranks, prefetched 256-wide
//   E  k_segment: per-batch boundary lists + frame->segment map
//   F  k_prefix : ragged row offsets
//   G  k_pool   : segment means (comp)
//   H  k_gi     : gi = comp @ W_ih^T + biases  [fp32 GEMM]
//   I  k_gru    : sequential GRU, one block/batch, W_hh f16 in VGPRs
//   J  k_scatter: out[b,t,:] = gru_out[b, seg(t), :]
// ---------------------------------------------------------------------------

#define NPOS 65537
#define KSEL 32768u
#define MAXROWS 32832

typedef _Float16 f16x2 __attribute__((ext_vector_type(2)));

#if defined(__has_builtin)
#if __has_builtin(__builtin_amdgcn_fdot2)
#define HAVE_FDOT2 1
#endif
#endif

__device__ __forceinline__ float fdot2f(f16x2 a, f16x2 b, float c) {
#ifdef HAVE_FDOT2
  return __builtin_amdgcn_fdot2(a, b, c, false);
#else
  c += (float)a.x * (float)b.x;
  c += (float)a.y * (float)b.y;
  return c;
#endif
}

// --------------------------- A: exact cumsums ------------------------------
// 8 blocks x 1 wave. Block b: sq=b>>2 (0: cs1 from x, 1: cs2 from x^2),
// cols j0=(b&3)*64 .. +63, lane = its column. Row-major output cs[p][j],
// p=0 row zeroed. LDS ring: 64 slots x 1KB (4 rows x 64 cols); issue depth
// 61 groups, s_waitcnt vmcnt(60) (FIFO: >=61 newer ops at each wait =>
// consumed slot's load retired). Stores batched 4 rows via LDS transpose.
template<bool SQ>
__device__ __forceinline__ void chain_run(const float* __restrict__ src,
                                          float* __restrict__ dst,
                                          int j0, float* ring,
                                          float (*stage)[68]) {
#pragma clang fp contract(off)
  const int l = threadIdx.x;
  dst[j0 + l] = 0.f;  // p=0 row (enc zero prepend)
  const float* gp = src + (size_t)((l >> 4) * 256 + j0 + (l & 15) * 4);
  for (int g = 0; g < 61; ++g) {
    __builtin_amdgcn_global_load_lds(
        (const __attribute__((address_space(1))) void*)gp,
        (__attribute__((address_space(3))) void*)(ring + (g << 8)), 16, 0, 0);
    gp += 1024;
  }
  float c = 0.f;
  float* sp = dst + (size_t)((1 + (l >> 4)) * 256 + j0 + (l & 15) * 4);
  const int srow = l >> 4, scol = (l & 15) * 4;
  int grp = 0;
  for (; grp < 16384 - 61; ++grp) {
    __builtin_amdgcn_global_load_lds(
        (const __attribute__((address_space(1))) void*)gp,
        (__attribute__((address_space(3))) void*)(ring + (((grp + 61) & 63) << 8)),
        16, 0, 0);
    gp += 1024;
    asm volatile("s_waitcnt vmcnt(60)" ::: "memory");
    const float* rb = ring + ((grp & 63) << 8);
    float v0 = rb[l], v1 = rb[64 + l], v2 = rb[128 + l], v3 = rb[192 + l];
    if (SQ) { v0 = v0 * v0; v1 = v1 * v1; v2 = v2 * v2; v3 = v3 * v3; }
    c = c + v0; stage[0][l] = c;
    c = c + v1; stage[1][l] = c;
    c = c + v2; stage[2][l] = c;
    c = c + v3; stage[3][l] = c;
    float4 sv = *(const float4*)&stage[srow][scol];
    *(float4*)sp = sv;
    sp += 1024;
  }
  asm volatile("s_waitcnt vmcnt(0)" ::: "memory");
  for (; grp < 16384; ++grp) {
    const float* rb = ring + ((grp & 63) << 8);
    float v0 = rb[l], v1 = rb[64 + l], v2 = rb[128 + l], v3 = rb[192 + l];
    if (SQ) { v0 = v0 * v0; v1 = v1 * v1; v2 = v2 * v2; v3 = v3 * v3; }
    c = c + v0; stage[0][l] = c;
    c = c + v1; stage[1][l] = c;
    c = c + v2; stage[2][l] = c;
    c = c + v3; stage[3][l] = c;
    float4 sv = *(const float4*)&stage[srow][scol];
    *(float4*)sp = sv;
    sp += 1024;
  }
}

__global__ __launch_bounds__(64) void k_chain(const float* __restrict__ x,
                                              float* __restrict__ cs1,
                                              float* __restrict__ cs2) {
  __shared__ float ring[64 * 256];   // 64 KB
  __shared__ float stage[4][68];
  const int sq = blockIdx.x >> 2;
  const int j0 = (blockIdx.x & 3) * 64;
  if (sq) chain_run<true>(x, cs2, j0, ring, stage);
  else    chain_run<false>(x, cs1, j0, ring, stage);
}

// --------------------------- B: exact diffs --------------------------------
// Row-major cs. Same op order as numpy: s1/2, s2/2 (exact /2), pairwise mean
// (two 128-blocks, 8 accumulators, specific combine), sqrt via double.
__global__ __launch_bounds__(64) void k_diffs(const float* __restrict__ cs1,
                                              const float* __restrict__ cs2,
                                              float* __restrict__ diffs) {
#pragma clang fp contract(off)
  int p = blockIdx.x * 64 + threadIdx.x;
  if (p >= NPOS) return;
  if (p == 0 || p == NPOS - 1) { diffs[p] = 1e10f; return; }
  const float* am = cs1 + (size_t)(p - 1) * 256;
  const float* ap = cs1 + (size_t)(p + 1) * 256;
  const float* bm = cs2 + (size_t)(p - 1) * 256;
  const float* bp = cs2 + (size_t)(p + 1) * 256;
  float blk[2];
  for (int half = 0; half < 2; ++half) {
    float r[8];
#pragma unroll
    for (int t = 0; t < 8; ++t) {
      int j = half * 128 + t;
      float s1 = ap[j] - am[j];
      float s2 = bp[j] - bm[j];
      float t1 = s1 * 0.5f;
      float u = s2 * 0.5f;
      r[t] = u - t1 * t1;
    }
    for (int i = 1; i < 16; ++i) {
#pragma unroll
      for (int t = 0; t < 8; ++t) {
        int j = half * 128 + i * 8 + t;
        float s1 = ap[j] - am[j];
        float s2 = bp[j] - bm[j];
        float t1 = s1 * 0.5f;
        float u = s2 * 0.5f;
        r[t] += u - t1 * t1;
      }
    }
    blk[half] = ((r[0] + r[1]) + (r[2] + r[3])) + ((r[4] + r[5]) + (r[6] + r[7]));
  }
  float mean = (blk[0] + blk[1]) / 256.0f;
  float mx = mean > 0.0f ? mean : 0.0f;
  diffs[p] = (float)::sqrt((double)mx);
}

// --------------------------- C: radix select -------------------------------
__global__ void k_hist1(const float* __restrict__ diffs, unsigned* __restrict__ h1) {
  int p = blockIdx.x * 256 + threadIdx.x;
  if (p >= NPOS) return;
  unsigned key = __float_as_uint(diffs[p]);
  atomicAdd(&h1[key >> 16], 1u);
}

__global__ void k_sel_hi(const unsigned* __restrict__ h1, unsigned* __restrict__ meta) {
  __shared__ unsigned loc[256];
  int t = threadIdx.x;
  unsigned s = 0;
  for (int i = 0; i < 256; ++i) s += h1[t * 256 + i];
  loc[t] = s;
  __syncthreads();
  if (t == 0) {
    unsigned run = 0; int tt = 255;
    for (; tt > 0; --tt) { if (run + loc[tt] >= KSEL) break; run += loc[tt]; }
    unsigned r2 = run;
    for (int i = 255; i >= 0; --i) {
      unsigned c = h1[tt * 256 + i];
      if (r2 + c >= KSEL) { meta[0] = (unsigned)(tt * 256 + i); meta[1] = r2; break; }
      r2 += c;
    }
  }
}

__global__ void k_hist2(const float* __restrict__ diffs, const unsigned* __restrict__ meta,
                        unsigned* __restrict__ h2) {
  int p = blockIdx.x * 256 + threadIdx.x;
  if (p >= NPOS) return;
  unsigned key = __float_as_uint(diffs[p]);
  if ((key >> 16) == meta[0]) atomicAdd(&h2[key & 0xffffu], 1u);
}

__global__ void k_sel_lo(const unsigned* __restrict__ h2, unsigned* __restrict__ meta) {
  __shared__ unsigned loc[256];
  int t = threadIdx.x;
  unsigned s = 0;
  for (int i = 0; i < 256; ++i) s += h2[t * 256 + i];
  loc[t] = s;
  __syncthreads();
  if (t == 0) {
    unsigned remaining = KSEL - meta[1];
    unsigned run = 0; int tt = 255;
    for (; tt > 0; --tt) { if (run + loc[tt] >= remaining) break; run += loc[tt]; }
    unsigned r2 = run;
    for (int i = 255; i >= 0; --i) {
      unsigned c = h2[tt * 256 + i];
      if (r2 + c >= remaining) {
        meta[2] = (meta[0] << 16) | (unsigned)(tt * 256 + i);
        meta[3] = remaining - r2;
        break;
      }
      r2 += c;
    }
  }
}

// --------------------------- D: keep flags ---------------------------------
// Single wave, 256 positions/iter (4 sequential 64-chunks), next-iter loads
// prefetched. Stable tie ranks in index order == argsort(-diffs, stable)[:k].
__global__ __launch_bounds__(64) void k_keep(const float* __restrict__ diffs,
                                             const unsigned* __restrict__ meta,
                                             unsigned char* __restrict__ keep) {
  int lane = threadIdx.x;
  unsigned Kstar = meta[2], need = meta[3];
  unsigned base = 0;
  float v[4], nv[4];
#pragma unroll
  for (int q = 0; q < 4; ++q) nv[q] = diffs[q * 64 + lane];
  for (int it = 0; it < 257; ++it) {
#pragma unroll
    for (int q = 0; q < 4; ++q) v[q] = nv[q];
    if (it < 256) {
      int nb = (it + 1) * 256;
#pragma unroll
      for (int q = 0; q < 4; ++q) {
        int idx = nb + q * 64 + lane;
        nv[q] = (idx < NPOS) ? diffs[idx] : 0.f;
      }
    }
#pragma unroll
    for (int q = 0; q < 4; ++q) {
      int p = it * 256 + q * 64 + lane;
      bool valid = p < NPOS;
      unsigned key = valid ? __float_as_uint(v[q]) : 0u;
      bool eq = valid && (key == Kstar);
      unsigned long long m = __ballot(eq);
      unsigned rank = base + (unsigned)__popcll(m & ((1ull << lane) - 1ull));
      bool k = valid && ((key > Kstar) || (eq && rank < need) || ((p & 1023) == 0));
      if (valid) keep[p] = (unsigned char)k;
      base += (unsigned)__popcll(m);
    }
  }
}

// --------------------------- E: per-batch segments -------------------------
__global__ __launch_bounds__(1024) void k_segment(const unsigned char* __restrict__ keep,
                                                  int* __restrict__ segid,
                                                  int* __restrict__ bnd,
                                                  int* __restrict__ nseg) {
  __shared__ int s[1024];
  int b = blockIdx.x, t = threadIdx.x;
  int f = (t >= 1) ? (int)keep[b * 1024 + t] : 0;
  s[t] = f;
  __syncthreads();
  for (int off = 1; off < 1024; off <<= 1) {
    int v = s[t];
    int add = (t >= off) ? s[t - off] : 0;
    __syncthreads();
    s[t] = v + add;
    __syncthreads();
  }
  int sc = s[t];
  segid[b * 1024 + t] = sc;
  if (f) bnd[b * 1026 + sc] = t;
  if (t == 0) bnd[b * 1026] = 0;
  if (t == 1023) {
    int m = sc + 1;
    nseg[b] = m;
    bnd[b * 1026 + m] = 1024;
  }
}

__global__ __launch_bounds__(64) void k_prefix(const int* __restrict__ nseg,
                                               int* __restrict__ pref) {
  int lane = threadIdx.x;
  int s = nseg[lane];
  for (int off = 1; off < 64; off <<= 1) {
    int u = __shfl_up(s, off);
    if (lane >= off) s += u;
  }
  pref[lane + 1] = s;
  if (lane == 0) pref[0] = 0;
}

// --------------------------- G: segment means ------------------------------
__global__ __launch_bounds__(256) void k_pool(const float* __restrict__ x,
                                              const int* __restrict__ bnd,
                                              const int* __restrict__ nseg,
                                              const int* __restrict__ pref,
                                              float* __restrict__ comp) {
  int d = threadIdx.x;
  for (int s = 0; s < 32; ++s) {
    int sid = blockIdx.x * 32 + s;   // 0..65535
    int b = sid >> 10, li = sid & 1023;
    if (li >= nseg[b]) continue;
    int s0 = bnd[b * 1026 + li], e0 = bnd[b * 1026 + li + 1];
    float acc = 0.f;
    for (int t = s0; t < e0; ++t) acc += x[((size_t)b * 1024 + t) * 256 + d];
    comp[((size_t)pref[b] + li) * 256 + d] = acc / (float)(e0 - s0);
  }
}

// --------------------------- H: gi GEMM (fp32) -----------------------------
__global__ __launch_bounds__(256) void k_gi(const float* __restrict__ comp,
                                            const float* __restrict__ Wih,
                                            const float* __restrict__ bih,
                                            const float* __restrict__ bhh,
                                            const int* __restrict__ pref,
                                            float* __restrict__ gi) {
  int total = pref[64];
  int r0 = blockIdx.x * 64;
  if (r0 >= total) return;
  int c0 = blockIdx.y * 128;
  __shared__ float As[64][64];
  __shared__ float Bs[64 * 132];
  int tid = threadIdx.x;
  int rg = tid >> 5, cl = tid & 31;
  float acc[8][4];
#pragma unroll
  for (int i = 0; i < 8; ++i)
#pragma unroll
    for (int q = 0; q < 4; ++q) acc[i][q] = 0.f;

  for (int k0 = 0; k0 < 256; k0 += 64) {
#pragma unroll
    for (int i = 0; i < 4; ++i) {
      int idx = tid + i * 256;
      int row = idx >> 4, kq = idx & 15;
      int rr = r0 + row;
      float4 v;
      if (rr < total) v = *reinterpret_cast<const float4*>(comp + (size_t)rr * 256 + k0 + kq * 4);
      else { v.x = 0.f; v.y = 0.f; v.z = 0.f; v.w = 0.f; }
      *reinterpret_cast<float4*>(&As[row][kq * 4]) = v;
    }
#pragma unroll
    for (int i = 0; i < 8; ++i) {
      int idx = tid + i * 256;
      int row = idx >> 4, kq = idx & 15;
      float4 v = *reinterpret_cast<const float4*>(Wih + (size_t)(c0 + row) * 256 + k0 + kq * 4);
      Bs[(kq * 4 + 0) * 132 + row] = v.x;
      Bs[(kq * 4 + 1) * 132 + row] = v.y;
      Bs[(kq * 4 + 2) * 132 + row] = v.z;
      Bs[(kq * 4 + 3) * 132 + row] = v.w;
    }
    __syncthreads();
#pragma unroll 4
    for (int k = 0; k < 64; ++k) {
      float a[8], bv[4];
#pragma unroll
      for (int i = 0; i < 8; ++i) a[i] = As[rg * 8 + i][k];
#pragma unroll
      for (int q = 0; q < 4; ++q) bv[q] = Bs[k * 132 + cl + 32 * q];
#pragma unroll
      for (int i = 0; i < 8; ++i)
#pragma unroll
        for (int q = 0; q < 4; ++q) acc[i][q] += a[i] * bv[q];
    }
    __syncthreads();
  }
#pragma unroll
  for (int q = 0; q < 4; ++q) {
    int c = c0 + cl + 32 * q;
    float bias = bih[c] + (c < 512 ? bhh[c] : 0.f);
#pragma unroll
    for (int i = 0; i < 8; ++i) {
      int rr = r0 + rg * 8 + i;
      if (rr < total) gi[(size_t)rr * 768 + c] = acc[i][q] + bias;
    }
  }
}

// --------------------------- I: GRU ----------------------------------------
__global__ __launch_bounds__(512, 2) void k_gru(const float* __restrict__ gi,
                                                const float* __restrict__ Whh,
                                                const float* __restrict__ bhh,
                                                const int* __restrict__ nseg,
                                                const int* __restrict__ pref,
                                                float* __restrict__ gout) {
  int b = blockIdx.x;
  int t = threadIdx.x;
  int m = nseg[b];
  size_t base = (size_t)pref[b];

  f16x2 wf[128];
#pragma unroll
  for (int i = 0; i < 64; ++i) {
    float4 v = *reinterpret_cast<const float4*>(Whh + (size_t)t * 256 + i * 4);
    f16x2 lo; lo.x = (_Float16)v.x; lo.y = (_Float16)v.y;
    f16x2 hi; hi.x = (_Float16)v.z; hi.y = (_Float16)v.w;
    wf[2 * i] = lo; wf[2 * i + 1] = hi;
  }
  int nrow = 512 + (t >> 1);
  int koff = (t & 1) * 128;
  f16x2 wh[64];
#pragma unroll
  for (int i = 0; i < 32; ++i) {
    float4 v = *reinterpret_cast<const float4*>(Whh + (size_t)nrow * 256 + koff + i * 4);
    f16x2 lo; lo.x = (_Float16)v.x; lo.y = (_Float16)v.y;
    f16x2 hi; hi.x = (_Float16)v.z; hi.y = (_Float16)v.w;
    wh[2 * i] = lo; wh[2 * i + 1] = hi;
  }

  __shared__ f16x2 h2buf[128];
  __shared__ float hf[256];
  __shared__ float sg[512];
  __shared__ float pn[512];

  float bn = (t < 256) ? bhh[512 + t] : 0.f;
  if (t < 128) ((unsigned*)h2buf)[t] = 0u;
  if (t < 256) hf[t] = 0.f;
  __syncthreads();

  int hb = koff >> 1;

  for (int l = 0; l < m; ++l) {
    const float* girow = gi + (base + l) * 768;
    float gv = girow[t];
    float gn = (t < 256) ? girow[512 + t] : 0.f;

    float af0 = 0.f, af1 = 0.f;
#pragma unroll
    for (int i = 0; i < 64; ++i) {
      af0 = fdot2f(wf[2 * i],     h2buf[2 * i],     af0);
      af1 = fdot2f(wf[2 * i + 1], h2buf[2 * i + 1], af1);
    }
    float af = af0 + af1;
    float ah0 = 0.f, ah1 = 0.f;
#pragma unroll
    for (int i = 0; i < 32; ++i) {
      ah0 = fdot2f(wh[2 * i],     h2buf[hb + 2 * i],     ah0);
      ah1 = fdot2f(wh[2 * i + 1], h2buf[hb + 2 * i + 1], ah1);
    }
    float ah = ah0 + ah1;

    sg[t] = 1.f / (1.f + expf(-(gv + af)));
    pn[t] = ah;
    __syncthreads();
    if (t < 256) {
      float r = sg[t], z = sg[256 + t];
      float hn = pn[2 * t] + pn[2 * t + 1] + bn;
      float n = tanhf(gn + r * hn);
      float hnew = (1.f - z) * n + z * hf[t];
      hf[t] = hnew;
      ((_Float16*)h2buf)[t] = (_Float16)hnew;
      gout[(base + l) * 256 + t] = hnew;
    }
    __syncthreads();
  }
}

// --------------------------- J: scatter ------------------------------------
__global__ __launch_bounds__(256) void k_scatter(const float* __restrict__ gout,
                                                 const int* __restrict__ segid,
                                                 const int* __restrict__ pref,
                                                 float* __restrict__ out) {
  int d = threadIdx.x;
  for (int rr = 0; rr < 32; ++rr) {
    int row = blockIdx.x * 32 + rr;   // b*1024 + t
    int b = row >> 10;
    int l = segid[row];
    out[(size_t)row * 256 + d] = gout[((size_t)pref[b] + l) * 256 + d];
  }
}

// ---------------------------------------------------------------------------
extern "C" void kernel_launch(void* const* d_in, const int* in_sizes, int n_in,
                              void* d_out, int out_size, void* d_ws, size_t ws_size,
                              hipStream_t stream) {
  const float* x   = (const float*)d_in[0];
  const float* Wih = (const float*)d_in[1];
  const float* Whh = (const float*)d_in[2];
  const float* bih = (const float*)d_in[3];
  const float* bhh = (const float*)d_in[4];
  float* out = (float*)d_out;
  char* w = (char*)d_ws;

  // ws layout (bytes); comp/gout reuse the cumsum regions (dead after k_diffs)
  const size_t o_cs1   = 0;            // 67,110,912 (65537*256*4 padded)
  const size_t o_cs2   = 67110912;
  const size_t o_diffs = 134221824;    // 262,400
  const size_t o_h1    = 134484224;    // 262,144
  const size_t o_h2    = 134746368;    // 262,144
  const size_t o_meta  = 135008512;    // 256
  const size_t o_keep  = 135008768;    // 65,792
  const size_t o_segid = 135074560;    // 262,144
  const size_t o_bnd   = 135336704;    // 262,656
  const size_t o_nseg  = 135599360;    // 256
  const size_t o_pref  = 135599616;    // 512
  const size_t o_gi    = 135600128;    // 100,859,904
  const size_t NEED    = 236460032;
  if (ws_size < NEED) return;

  float* cs1 = (float*)(w + o_cs1);
  float* cs2 = (float*)(w + o_cs2);
  float* diffs = (float*)(w + o_diffs);
  unsigned* h1 = (unsigned*)(w + o_h1);
  unsigned* h2 = (unsigned*)(w + o_h2);
  unsigned* meta = (unsigned*)(w + o_meta);
  unsigned char* keep = (unsigned char*)(w + o_keep);
  int* segid = (int*)(w + o_segid);
  int* bnd = (int*)(w + o_bnd);
  int* nseg = (int*)(w + o_nseg);
  int* pref = (int*)(w + o_pref);
  float* gi = (float*)(w + o_gi);
  float* comp = cs1;  // reuse
  float* gout = cs2;  // reuse

  hipMemsetAsync(h1, 0, 262144, stream);
  hipMemsetAsync(h2, 0, 262144, stream);

  k_chain  <<<dim3(8),      dim3(64),   0, stream>>>(x, cs1, cs2);
  k_diffs  <<<dim3(1025),   dim3(64),   0, stream>>>(cs1, cs2, diffs);
  k_hist1  <<<dim3(257),    dim3(256),  0, stream>>>(diffs, h1);
  k_sel_hi <<<dim3(1),      dim3(256),  0, stream>>>(h1, meta);
  k_hist2  <<<dim3(257),    dim3(256),  0, stream>>>(diffs, meta, h2);
  k_sel_lo <<<dim3(1),      dim3(256),  0, stream>>>(h2, meta);
  k_keep   <<<dim3(1),      dim3(64),   0, stream>>>(diffs, meta, keep);
  k_segment<<<dim3(64),     dim3(1024), 0, stream>>>(keep, segid, bnd, nseg);
  k_prefix <<<dim3(1),      dim3(64),   0, stream>>>(nseg, pref);
  k_pool   <<<dim3(2048),   dim3(256),  0, stream>>>(x, bnd, nseg, pref, comp);
  k_gi     <<<dim3(513, 6), dim3(256),  0, stream>>>(comp, Wih, bih, bhh, pref, gi);
  k_gru    <<<dim3(64),     dim3(512),  0, stream>>>(gi, Whh, bhh, nseg, pref, gout);
  k_scatter<<<dim3(2048),   dim3(256),  0, stream>>>(gout, segid, pref, out);
}

// Round 3
// 2596.075 us; speedup vs baseline: 3.0484x; 3.0484x over previous
//
#include <hip/hip_runtime.h>
#include <cstdint>
#include <cstddef>
#include <cmath>

// ---------------------------------------------------------------------------
// Pipeline:
//   A  k_chain  : exact sequential float32 cumsums, register-rotation
//                 software pipeline (no LDS), 8 blocks x 1 wave
//   B  k_diffs  : exact numpy-pairwise variance->diffs per position
//   C  k_hist1/k_sel_hi/k_hist2/k_sel_lo : exact top-32768 radix select
//   D  k_keep   : keep flags, stable tie ranks, prefetched 256-wide
//   E  k_segment: per-batch boundary lists + frame->segment map
//   F  k_prefix : ragged row offsets
//   G  k_pool   : segment means (comp)
//   H  k_gi     : gi = comp @ W_ih^T + biases  [fp32 GEMM]
//   I  k_gru    : sequential GRU, one block/batch, W_hh f16 in VGPRs
//   J  k_scatter: out[b,t,:] = gru_out[b, seg(t), :]
// ---------------------------------------------------------------------------

#define NPOS 65537
#define KSEL 32768u
#define MAXROWS 32832

typedef _Float16 f16x2 __attribute__((ext_vector_type(2)));

#if defined(__has_builtin)
#if __has_builtin(__builtin_amdgcn_fdot2)
#define HAVE_FDOT2 1
#endif
#endif

__device__ __forceinline__ float fdot2f(f16x2 a, f16x2 b, float c) {
#ifdef HAVE_FDOT2
  return __builtin_amdgcn_fdot2(a, b, c, false);
#else
  c += (float)a.x * (float)b.x;
  c += (float)a.y * (float)b.y;
  return c;
#endif
}

// --------------------------- A: exact cumsums ------------------------------
// 8 blocks x 64 lanes. Block b: SQ=b>>2 (0: cs1 from x, 1: cs2 from x^2),
// columns j0=(b&3)*64 .. +63; lane l owns column j0+l (serial chain over
// 65536 rows). Row-major output cs[p][j], row p=0 zeroed.
// Register pipeline: D=4 groups x U=32 rows in flight (96 rows ahead);
// rotation index static after unroll so buf stays in VGPRs. No LDS, no
// inline-asm fences -> compiler emits counted vmcnt itself.
template<bool SQ>
__device__ __forceinline__ void chain_run(const float* __restrict__ src,
                                          float* __restrict__ dst, int j0) {
#pragma clang fp contract(off)
  const int l = threadIdx.x;
  constexpr int U = 32;
  constexpr int D = 4;
  constexpr int NG = 65536 / U;   // 2048 groups
  const float* gp = src + j0 + l;
  float* sp = dst + 256 + j0 + l;
  dst[j0 + l] = 0.f;              // p=0 row (enc zero prepend)
  float buf[D][U];
#pragma unroll
  for (int d = 0; d < D - 1; ++d)
#pragma unroll
    for (int u = 0; u < U; ++u)
      buf[d][u] = gp[(size_t)(d * U + u) * 256];
  float c = 0.f;
  for (int g = 0; g < NG / D; ++g) {
#pragma unroll
    for (int d = 0; d < D; ++d) {
      const int s = g * D + d;           // current group (uniform scalar)
      if (s + D - 1 < NG) {              // issue prefetch, 3 groups ahead
        const float* ld = gp + (size_t)(s + D - 1) * U * 256;
#pragma unroll
        for (int u = 0; u < U; ++u)
          buf[(d + D - 1) % D][u] = ld[(size_t)u * 256];
      }
      float* st = sp + (size_t)s * U * 256;
#pragma unroll
      for (int u = 0; u < U; ++u) {
        float v = buf[d][u];
        if (SQ) v = v * v;               // rounded square, then add (no FMA)
        c = c + v;
        st[(size_t)u * 256] = c;
      }
    }
  }
}

__global__ __launch_bounds__(64) void k_chain(const float* __restrict__ x,
                                              float* __restrict__ cs1,
                                              float* __restrict__ cs2) {
  const int sq = blockIdx.x >> 2;
  const int j0 = (blockIdx.x & 3) * 64;
  if (sq) chain_run<true>(x, cs2, j0);
  else    chain_run<false>(x, cs1, j0);
}

// --------------------------- B: exact diffs --------------------------------
// Row-major cs. Same op order as numpy: s1/2, s2/2 (exact /2), pairwise mean
// (two 128-blocks, 8 accumulators, specific combine), sqrt via double.
__global__ __launch_bounds__(64) void k_diffs(const float* __restrict__ cs1,
                                              const float* __restrict__ cs2,
                                              float* __restrict__ diffs) {
#pragma clang fp contract(off)
  int p = blockIdx.x * 64 + threadIdx.x;
  if (p >= NPOS) return;
  if (p == 0 || p == NPOS - 1) { diffs[p] = 1e10f; return; }
  const float* am = cs1 + (size_t)(p - 1) * 256;
  const float* ap = cs1 + (size_t)(p + 1) * 256;
  const float* bm = cs2 + (size_t)(p - 1) * 256;
  const float* bp = cs2 + (size_t)(p + 1) * 256;
  float blk[2];
  for (int half = 0; half < 2; ++half) {
    float r[8];
#pragma unroll
    for (int t = 0; t < 8; ++t) {
      int j = half * 128 + t;
      float s1 = ap[j] - am[j];
      float s2 = bp[j] - bm[j];
      float t1 = s1 * 0.5f;
      float u = s2 * 0.5f;
      r[t] = u - t1 * t1;
    }
    for (int i = 1; i < 16; ++i) {
#pragma unroll
      for (int t = 0; t < 8; ++t) {
        int j = half * 128 + i * 8 + t;
        float s1 = ap[j] - am[j];
        float s2 = bp[j] - bm[j];
        float t1 = s1 * 0.5f;
        float u = s2 * 0.5f;
        r[t] += u - t1 * t1;
      }
    }
    blk[half] = ((r[0] + r[1]) + (r[2] + r[3])) + ((r[4] + r[5]) + (r[6] + r[7]));
  }
  float mean = (blk[0] + blk[1]) / 256.0f;
  float mx = mean > 0.0f ? mean : 0.0f;
  diffs[p] = (float)::sqrt((double)mx);
}

// --------------------------- C: radix select -------------------------------
__global__ void k_hist1(const float* __restrict__ diffs, unsigned* __restrict__ h1) {
  int p = blockIdx.x * 256 + threadIdx.x;
  if (p >= NPOS) return;
  unsigned key = __float_as_uint(diffs[p]);
  atomicAdd(&h1[key >> 16], 1u);
}

__global__ void k_sel_hi(const unsigned* __restrict__ h1, unsigned* __restrict__ meta) {
  __shared__ unsigned loc[256];
  int t = threadIdx.x;
  unsigned s = 0;
  for (int i = 0; i < 256; ++i) s += h1[t * 256 + i];
  loc[t] = s;
  __syncthreads();
  if (t == 0) {
    unsigned run = 0; int tt = 255;
    for (; tt > 0; --tt) { if (run + loc[tt] >= KSEL) break; run += loc[tt]; }
    unsigned r2 = run;
    for (int i = 255; i >= 0; --i) {
      unsigned c = h1[tt * 256 + i];
      if (r2 + c >= KSEL) { meta[0] = (unsigned)(tt * 256 + i); meta[1] = r2; break; }
      r2 += c;
    }
  }
}

__global__ void k_hist2(const float* __restrict__ diffs, const unsigned* __restrict__ meta,
                        unsigned* __restrict__ h2) {
  int p = blockIdx.x * 256 + threadIdx.x;
  if (p >= NPOS) return;
  unsigned key = __float_as_uint(diffs[p]);
  if ((key >> 16) == meta[0]) atomicAdd(&h2[key & 0xffffu], 1u);
}

__global__ void k_sel_lo(const unsigned* __restrict__ h2, unsigned* __restrict__ meta) {
  __shared__ unsigned loc[256];
  int t = threadIdx.x;
  unsigned s = 0;
  for (int i = 0; i < 256; ++i) s += h2[t * 256 + i];
  loc[t] = s;
  __syncthreads();
  if (t == 0) {
    unsigned remaining = KSEL - meta[1];
    unsigned run = 0; int tt = 255;
    for (; tt > 0; --tt) { if (run + loc[tt] >= remaining) break; run += loc[tt]; }
    unsigned r2 = run;
    for (int i = 255; i >= 0; --i) {
      unsigned c = h2[tt * 256 + i];
      if (r2 + c >= remaining) {
        meta[2] = (meta[0] << 16) | (unsigned)(tt * 256 + i);
        meta[3] = remaining - r2;
        break;
      }
      r2 += c;
    }
  }
}

// --------------------------- D: keep flags ---------------------------------
__global__ __launch_bounds__(64) void k_keep(const float* __restrict__ diffs,
                                             const unsigned* __restrict__ meta,
                                             unsigned char* __restrict__ keep) {
  int lane = threadIdx.x;
  unsigned Kstar = meta[2], need = meta[3];
  unsigned base = 0;
  float v[4], nv[4];
#pragma unroll
  for (int q = 0; q < 4; ++q) nv[q] = diffs[q * 64 + lane];
  for (int it = 0; it < 257; ++it) {
#pragma unroll
    for (int q = 0; q < 4; ++q) v[q] = nv[q];
    if (it < 256) {
      int nb = (it + 1) * 256;
#pragma unroll
      for (int q = 0; q < 4; ++q) {
        int idx = nb + q * 64 + lane;
        nv[q] = (idx < NPOS) ? diffs[idx] : 0.f;
      }
    }
#pragma unroll
    for (int q = 0; q < 4; ++q) {
      int p = it * 256 + q * 64 + lane;
      bool valid = p < NPOS;
      unsigned key = valid ? __float_as_uint(v[q]) : 0u;
      bool eq = valid && (key == Kstar);
      unsigned long long m = __ballot(eq);
      unsigned rank = base + (unsigned)__popcll(m & ((1ull << lane) - 1ull));
      bool k = valid && ((key > Kstar) || (eq && rank < need) || ((p & 1023) == 0));
      if (valid) keep[p] = (unsigned char)k;
      base += (unsigned)__popcll(m);
    }
  }
}

// --------------------------- E: per-batch segments -------------------------
__global__ __launch_bounds__(1024) void k_segment(const unsigned char* __restrict__ keep,
                                                  int* __restrict__ segid,
                                                  int* __restrict__ bnd,
                                                  int* __restrict__ nseg) {
  __shared__ int s[1024];
  int b = blockIdx.x, t = threadIdx.x;
  int f = (t >= 1) ? (int)keep[b * 1024 + t] : 0;
  s[t] = f;
  __syncthreads();
  for (int off = 1; off < 1024; off <<= 1) {
    int v = s[t];
    int add = (t >= off) ? s[t - off] : 0;
    __syncthreads();
    s[t] = v + add;
    __syncthreads();
  }
  int sc = s[t];
  segid[b * 1024 + t] = sc;
  if (f) bnd[b * 1026 + sc] = t;
  if (t == 0) bnd[b * 1026] = 0;
  if (t == 1023) {
    int m = sc + 1;
    nseg[b] = m;
    bnd[b * 1026 + m] = 1024;
  }
}

__global__ __launch_bounds__(64) void k_prefix(const int* __restrict__ nseg,
                                               int* __restrict__ pref) {
  int lane = threadIdx.x;
  int s = nseg[lane];
  for (int off = 1; off < 64; off <<= 1) {
    int u = __shfl_up(s, off);
    if (lane >= off) s += u;
  }
  pref[lane + 1] = s;
  if (lane == 0) pref[0] = 0;
}

// --------------------------- G: segment means ------------------------------
__global__ __launch_bounds__(256) void k_pool(const float* __restrict__ x,
                                              const int* __restrict__ bnd,
                                              const int* __restrict__ nseg,
                                              const int* __restrict__ pref,
                                              float* __restrict__ comp) {
  int d = threadIdx.x;
  for (int s = 0; s < 32; ++s) {
    int sid = blockIdx.x * 32 + s;   // 0..65535
    int b = sid >> 10, li = sid & 1023;
    if (li >= nseg[b]) continue;
    int s0 = bnd[b * 1026 + li], e0 = bnd[b * 1026 + li + 1];
    float acc = 0.f;
    for (int t = s0; t < e0; ++t) acc += x[((size_t)b * 1024 + t) * 256 + d];
    comp[((size_t)pref[b] + li) * 256 + d] = acc / (float)(e0 - s0);
  }
}

// --------------------------- H: gi GEMM (fp32) -----------------------------
__global__ __launch_bounds__(256) void k_gi(const float* __restrict__ comp,
                                            const float* __restrict__ Wih,
                                            const float* __restrict__ bih,
                                            const float* __restrict__ bhh,
                                            const int* __restrict__ pref,
                                            float* __restrict__ gi) {
  int total = pref[64];
  int r0 = blockIdx.x * 64;
  if (r0 >= total) return;
  int c0 = blockIdx.y * 128;
  __shared__ float As[64][64];
  __shared__ float Bs[64 * 132];
  int tid = threadIdx.x;
  int rg = tid >> 5, cl = tid & 31;
  float acc[8][4];
#pragma unroll
  for (int i = 0; i < 8; ++i)
#pragma unroll
    for (int q = 0; q < 4; ++q) acc[i][q] = 0.f;

  for (int k0 = 0; k0 < 256; k0 += 64) {
#pragma unroll
    for (int i = 0; i < 4; ++i) {
      int idx = tid + i * 256;
      int row = idx >> 4, kq = idx & 15;
      int rr = r0 + row;
      float4 v;
      if (rr < total) v = *reinterpret_cast<const float4*>(comp + (size_t)rr * 256 + k0 + kq * 4);
      else { v.x = 0.f; v.y = 0.f; v.z = 0.f; v.w = 0.f; }
      *reinterpret_cast<float4*>(&As[row][kq * 4]) = v;
    }
#pragma unroll
    for (int i = 0; i < 8; ++i) {
      int idx = tid + i * 256;
      int row = idx >> 4, kq = idx & 15;
      float4 v = *reinterpret_cast<const float4*>(Wih + (size_t)(c0 + row) * 256 + k0 + kq * 4);
      Bs[(kq * 4 + 0) * 132 + row] = v.x;
      Bs[(kq * 4 + 1) * 132 + row] = v.y;
      Bs[(kq * 4 + 2) * 132 + row] = v.z;
      Bs[(kq * 4 + 3) * 132 + row] = v.w;
    }
    __syncthreads();
#pragma unroll 4
    for (int k = 0; k < 64; ++k) {
      float a[8], bv[4];
#pragma unroll
      for (int i = 0; i < 8; ++i) a[i] = As[rg * 8 + i][k];
#pragma unroll
      for (int q = 0; q < 4; ++q) bv[q] = Bs[k * 132 + cl + 32 * q];
#pragma unroll
      for (int i = 0; i < 8; ++i)
#pragma unroll
        for (int q = 0; q < 4; ++q) acc[i][q] += a[i] * bv[q];
    }
    __syncthreads();
  }
#pragma unroll
  for (int q = 0; q < 4; ++q) {
    int c = c0 + cl + 32 * q;
    float bias = bih[c] + (c < 512 ? bhh[c] : 0.f);
#pragma unroll
    for (int i = 0; i < 8; ++i) {
      int rr = r0 + rg * 8 + i;
      if (rr < total) gi[(size_t)rr * 768 + c] = acc[i][q] + bias;
    }
  }
}

// --------------------------- I: GRU ----------------------------------------
__global__ __launch_bounds__(512, 2) void k_gru(const float* __restrict__ gi,
                                                const float* __restrict__ Whh,
                                                const float* __restrict__ bhh,
                                                const int* __restrict__ nseg,
                                                const int* __restrict__ pref,
                                                float* __restrict__ gout) {
  int b = blockIdx.x;
  int t = threadIdx.x;
  int m = nseg[b];
  size_t base = (size_t)pref[b];

  f16x2 wf[128];
#pragma unroll
  for (int i = 0; i < 64; ++i) {
    float4 v = *reinterpret_cast<const float4*>(Whh + (size_t)t * 256 + i * 4);
    f16x2 lo; lo.x = (_Float16)v.x; lo.y = (_Float16)v.y;
    f16x2 hi; hi.x = (_Float16)v.z; hi.y = (_Float16)v.w;
    wf[2 * i] = lo; wf[2 * i + 1] = hi;
  }
  int nrow = 512 + (t >> 1);
  int koff = (t & 1) * 128;
  f16x2 wh[64];
#pragma unroll
  for (int i = 0; i < 32; ++i) {
    float4 v = *reinterpret_cast<const float4*>(Whh + (size_t)nrow * 256 + koff + i * 4);
    f16x2 lo; lo.x = (_Float16)v.x; lo.y = (_Float16)v.y;
    f16x2 hi; hi.x = (_Float16)v.z; hi.y = (_Float16)v.w;
    wh[2 * i] = lo; wh[2 * i + 1] = hi;
  }

  __shared__ f16x2 h2buf[128];
  __shared__ float hf[256];
  __shared__ float sg[512];
  __shared__ float pn[512];

  float bn = (t < 256) ? bhh[512 + t] : 0.f;
  if (t < 128) ((unsigned*)h2buf)[t] = 0u;
  if (t < 256) hf[t] = 0.f;
  __syncthreads();

  int hb = koff >> 1;

  for (int l = 0; l < m; ++l) {
    const float* girow = gi + (base + l) * 768;
    float gv = girow[t];
    float gn = (t < 256) ? girow[512 + t] : 0.f;

    float af0 = 0.f, af1 = 0.f;
#pragma unroll
    for (int i = 0; i < 64; ++i) {
      af0 = fdot2f(wf[2 * i],     h2buf[2 * i],     af0);
      af1 = fdot2f(wf[2 * i + 1], h2buf[2 * i + 1], af1);
    }
    float af = af0 + af1;
    float ah0 = 0.f, ah1 = 0.f;
#pragma unroll
    for (int i = 0; i < 32; ++i) {
      ah0 = fdot2f(wh[2 * i],     h2buf[hb + 2 * i],     ah0);
      ah1 = fdot2f(wh[2 * i + 1], h2buf[hb + 2 * i + 1], ah1);
    }
    float ah = ah0 + ah1;

    sg[t] = 1.f / (1.f + expf(-(gv + af)));
    pn[t] = ah;
    __syncthreads();
    if (t < 256) {
      float r = sg[t], z = sg[256 + t];
      float hn = pn[2 * t] + pn[2 * t + 1] + bn;
      float n = tanhf(gn + r * hn);
      float hnew = (1.f - z) * n + z * hf[t];
      hf[t] = hnew;
      ((_Float16*)h2buf)[t] = (_Float16)hnew;
      gout[(base + l) * 256 + t] = hnew;
    }
    __syncthreads();
  }
}

// --------------------------- J: scatter ------------------------------------
__global__ __launch_bounds__(256) void k_scatter(const float* __restrict__ gout,
                                                 const int* __restrict__ segid,
                                                 const int* __restrict__ pref,
                                                 float* __restrict__ out) {
  int d = threadIdx.x;
  for (int rr = 0; rr < 32; ++rr) {
    int row = blockIdx.x * 32 + rr;   // b*1024 + t
    int b = row >> 10;
    int l = segid[row];
    out[(size_t)row * 256 + d] = gout[((size_t)pref[b] + l) * 256 + d];
  }
}

// ---------------------------------------------------------------------------
extern "C" void kernel_launch(void* const* d_in, const int* in_sizes, int n_in,
                              void* d_out, int out_size, void* d_ws, size_t ws_size,
                              hipStream_t stream) {
  const float* x   = (const float*)d_in[0];
  const float* Wih = (const float*)d_in[1];
  const float* Whh = (const float*)d_in[2];
  const float* bih = (const float*)d_in[3];
  const float* bhh = (const float*)d_in[4];
  float* out = (float*)d_out;
  char* w = (char*)d_ws;

  // ws layout (bytes); comp/gout reuse the cumsum regions (dead after k_diffs)
  const size_t o_cs1   = 0;            // 67,110,912 (65537*256*4 padded)
  const size_t o_cs2   = 67110912;
  const size_t o_diffs = 134221824;    // 262,400
  const size_t o_h1    = 134484224;    // 262,144
  const size_t o_h2    = 134746368;    // 262,144
  const size_t o_meta  = 135008512;    // 256
  const size_t o_keep  = 135008768;    // 65,792
  const size_t o_segid = 135074560;    // 262,144
  const size_t o_bnd   = 135336704;    // 262,656
  const size_t o_nseg  = 135599360;    // 256
  const size_t o_pref  = 135599616;    // 512
  const size_t o_gi    = 135600128;    // 100,859,904
  const size_t NEED    = 236460032;
  if (ws_size < NEED) return;

  float* cs1 = (float*)(w + o_cs1);
  float* cs2 = (float*)(w + o_cs2);
  float* diffs = (float*)(w + o_diffs);
  unsigned* h1 = (unsigned*)(w + o_h1);
  unsigned* h2 = (unsigned*)(w + o_h2);
  unsigned* meta = (unsigned*)(w + o_meta);
  unsigned char* keep = (unsigned char*)(w + o_keep);
  int* segid = (int*)(w + o_segid);
  int* bnd = (int*)(w + o_bnd);
  int* nseg = (int*)(w + o_nseg);
  int* pref = (int*)(w + o_pref);
  float* gi = (float*)(w + o_gi);
  float* comp = cs1;  // reuse
  float* gout = cs2;  // reuse

  hipMemsetAsync(h1, 0, 262144, stream);
  hipMemsetAsync(h2, 0, 262144, stream);

  k_chain  <<<dim3(8),      dim3(64),   0, stream>>>(x, cs1, cs2);
  k_diffs  <<<dim3(1025),   dim3(64),   0, stream>>>(cs1, cs2, diffs);
  k_hist1  <<<dim3(257),    dim3(256),  0, stream>>>(diffs, h1);
  k_sel_hi <<<dim3(1),      dim3(256),  0, stream>>>(h1, meta);
  k_hist2  <<<dim3(257),    dim3(256),  0, stream>>>(diffs, meta, h2);
  k_sel_lo <<<dim3(1),      dim3(256),  0, stream>>>(h2, meta);
  k_keep   <<<dim3(1),      dim3(64),   0, stream>>>(diffs, meta, keep);
  k_segment<<<dim3(64),     dim3(1024), 0, stream>>>(keep, segid, bnd, nseg);
  k_prefix <<<dim3(1),      dim3(64),   0, stream>>>(nseg, pref);
  k_pool   <<<dim3(2048),   dim3(256),  0, stream>>>(x, bnd, nseg, pref, comp);
  k_gi     <<<dim3(513, 6), dim3(256),  0, stream>>>(comp, Wih, bih, bhh, pref, gi);
  k_gru    <<<dim3(64),     dim3(512),  0, stream>>>(gi, Whh, bhh, nseg, pref, gout);
  k_scatter<<<dim3(2048),   dim3(256),  0, stream>>>(gout, segid, pref, out);
}

// Round 4
// 2551.723 us; speedup vs baseline: 3.1014x; 1.0174x over previous
//
#include <hip/hip_runtime.h>
#include <cstdint>
#include <cstddef>
#include <cmath>

// ---------------------------------------------------------------------------
// Pipeline:
//   A0 k_warm   : pull x into L2/L3 (full-GPU streaming read, ~13us)
//   A  k_chain  : exact sequential float32 cumsums; per block: 1 chain wave
//                 (loads-only VMEM FIFO, register pipeline) + 3 writer waves
//                 draining a double-buffered LDS ring (raw s_barrier sync)
//   B  k_diffs  : exact numpy-pairwise variance->diffs per position
//   C  k_hist1/k_sel_hi/k_hist2/k_sel_lo : exact top-32768 radix select
//   D  k_keep   : keep flags, stable tie ranks
//   E  k_segment: per-batch boundary lists + frame->segment map
//   F  k_prefix : ragged row offsets
//   G  k_pool   : segment means (comp)
//   H  k_gi     : gi = comp @ W_ih^T + biases  [fp32 GEMM]
//   I  k_gru    : sequential GRU, one block/batch, W_hh f16 in VGPRs
//   J  k_scatter: out[b,t,:] = gru_out[b, seg(t), :]
// ---------------------------------------------------------------------------

#define NPOS 65537
#define KSEL 32768u

typedef _Float16 f16x2 __attribute__((ext_vector_type(2)));

#if defined(__has_builtin)
#if __has_builtin(__builtin_amdgcn_fdot2)
#define HAVE_FDOT2 1
#endif
#endif

__device__ __forceinline__ float fdot2f(f16x2 a, f16x2 b, float c) {
#ifdef HAVE_FDOT2
  return __builtin_amdgcn_fdot2(a, b, c, false);
#else
  c += (float)a.x * (float)b.x;
  c += (float)a.y * (float)b.y;
  return c;
#endif
}

// --------------------------- A0: warm x into cache -------------------------
__global__ __launch_bounds__(256) void k_warm(const float4* __restrict__ x4,
                                              float* __restrict__ sink) {
  size_t i = (size_t)blockIdx.x * 256 + threadIdx.x;
  float4 v = x4[i];
  float s = (v.x + v.y) + (v.z + v.w);
  if (s == 1.23456789e-33f) sink[0] = s;  // deterministically false; keeps loads
}

// --------------------------- A: exact cumsums ------------------------------
// 8 blocks x 256 threads (4 waves). Block b: SQ=b>>2 (cs1 vs cs2),
// cols j0=(b&3)*64. Wave 0 = chain (lane l owns column j0+l, serial over
// 65536 rows); waves 1-3 = writers. Chunk = 128 rows; LDS ring = 2 chunks.
// Chain wave's VMEM FIFO holds ONLY loads (48 in flight, D=4 x U=16
// rotation) -> exact counted vmcnt, full prefetch depth. Results go to the
// ring via ds_write (lgkmcnt); writers do the coalesced global stores.
template<bool SQ>
__device__ __forceinline__ void chain_fill(const float* __restrict__ gp,
                                           float* __restrict__ ring,
                                           float buf[4][16], float& c,
                                           int chunk, int l) {
#pragma clang fp contract(off)
  float* rb = ring + (chunk & 1) * (128 * 64);
#pragma unroll
  for (int s8 = 0; s8 < 8; ++s8) {
    const int step = chunk * 8 + s8;
    const int d = s8 & 3;
    const int pd = (s8 + 3) & 3;
    if (step + 3 < 4096) {
      const float* ld = gp + (size_t)(step + 3) * 16 * 256;
#pragma unroll
      for (int u = 0; u < 16; ++u)
        buf[pd][u] = ld[(size_t)u * 256];
    }
#pragma unroll
    for (int u = 0; u < 16; ++u) {
      float v = buf[d][u];
      if (SQ) v = v * v;          // rounded square, then add (no FMA)
      c = c + v;
      rb[(s8 * 16 + u) * 64 + l] = c;
    }
  }
}

template<bool SQ>
__device__ __forceinline__ void chain_loop(const float* __restrict__ src,
                                           int j0, float* __restrict__ ring,
                                           int l) {
#pragma clang fp contract(off)
  const float* gp = src + j0 + l;
  float buf[4][16];
#pragma unroll
  for (int d = 0; d < 3; ++d)
#pragma unroll
    for (int u = 0; u < 16; ++u)
      buf[d][u] = gp[(size_t)(d * 16 + u) * 256];
  float c = 0.f;
  for (int it = 0; it <= 512; ++it) {
    if (it < 512) chain_fill<SQ>(gp, ring, buf, c, it, l);
    asm volatile("s_waitcnt lgkmcnt(0)" ::: "memory");
    __builtin_amdgcn_s_barrier();
    __builtin_amdgcn_sched_barrier(0);
  }
}

__device__ __forceinline__ void writer_loop(const float* __restrict__ ring,
                                            float* __restrict__ dst, int j0,
                                            int w /*0..2*/, int l) {
  if (w == 0) dst[j0 + l] = 0.f;  // global row 0 (enc zero prepend)
  for (int it = 0; it <= 512; ++it) {
    if (it >= 1) {
      const float* rb = ring + ((it - 1) & 1) * (128 * 64);
      float* gb = dst + (size_t)((it - 1) * 128 + 1) * 256 + j0 + l;
      for (int r = w; r < 128; r += 3)
        gb[(size_t)r * 256] = rb[r * 64 + l];
    }
    __builtin_amdgcn_s_barrier();
    __builtin_amdgcn_sched_barrier(0);
  }
}

__global__ __launch_bounds__(256) void k_chain(const float* __restrict__ x,
                                               float* __restrict__ cs1,
                                               float* __restrict__ cs2) {
  __shared__ float ring[2 * 128 * 64];  // 64 KiB
  const int sq = blockIdx.x >> 2;
  const int j0 = (blockIdx.x & 3) * 64;
  const int wid = threadIdx.x >> 6;
  const int l = threadIdx.x & 63;
  float* dst = sq ? cs2 : cs1;
  if (wid == 0) {
    if (sq) chain_loop<true>(x, j0, ring, l);
    else    chain_loop<false>(x, j0, ring, l);
  } else {
    writer_loop(ring, dst, j0, wid - 1, l);
  }
}

// --------------------------- B: exact diffs --------------------------------
__global__ __launch_bounds__(64) void k_diffs(const float* __restrict__ cs1,
                                              const float* __restrict__ cs2,
                                              float* __restrict__ diffs) {
#pragma clang fp contract(off)
  int p = blockIdx.x * 64 + threadIdx.x;
  if (p >= NPOS) return;
  if (p == 0 || p == NPOS - 1) { diffs[p] = 1e10f; return; }
  const float* am = cs1 + (size_t)(p - 1) * 256;
  const float* ap = cs1 + (size_t)(p + 1) * 256;
  const float* bm = cs2 + (size_t)(p - 1) * 256;
  const float* bp = cs2 + (size_t)(p + 1) * 256;
  float blk[2];
  for (int half = 0; half < 2; ++half) {
    float r[8];
#pragma unroll
    for (int t = 0; t < 8; ++t) {
      int j = half * 128 + t;
      float s1 = ap[j] - am[j];
      float s2 = bp[j] - bm[j];
      float t1 = s1 * 0.5f;
      float u = s2 * 0.5f;
      r[t] = u - t1 * t1;
    }
    for (int i = 1; i < 16; ++i) {
#pragma unroll
      for (int t = 0; t < 8; ++t) {
        int j = half * 128 + i * 8 + t;
        float s1 = ap[j] - am[j];
        float s2 = bp[j] - bm[j];
        float t1 = s1 * 0.5f;
        float u = s2 * 0.5f;
        r[t] += u - t1 * t1;
      }
    }
    blk[half] = ((r[0] + r[1]) + (r[2] + r[3])) + ((r[4] + r[5]) + (r[6] + r[7]));
  }
  float mean = (blk[0] + blk[1]) / 256.0f;
  float mx = mean > 0.0f ? mean : 0.0f;
  diffs[p] = (float)::sqrt((double)mx);
}

// --------------------------- C: radix select -------------------------------
__global__ void k_hist1(const float* __restrict__ diffs, unsigned* __restrict__ h1) {
  int p = blockIdx.x * 256 + threadIdx.x;
  if (p >= NPOS) return;
  unsigned key = __float_as_uint(diffs[p]);
  atomicAdd(&h1[key >> 16], 1u);
}

__global__ void k_sel_hi(const unsigned* __restrict__ h1, unsigned* __restrict__ meta) {
  __shared__ unsigned loc[256];
  int t = threadIdx.x;
  unsigned s = 0;
  for (int i = 0; i < 256; ++i) s += h1[t * 256 + i];
  loc[t] = s;
  __syncthreads();
  if (t == 0) {
    unsigned run = 0; int tt = 255;
    for (; tt > 0; --tt) { if (run + loc[tt] >= KSEL) break; run += loc[tt]; }
    unsigned r2 = run;
    for (int i = 255; i >= 0; --i) {
      unsigned c = h1[tt * 256 + i];
      if (r2 + c >= KSEL) { meta[0] = (unsigned)(tt * 256 + i); meta[1] = r2; break; }
      r2 += c;
    }
  }
}

__global__ void k_hist2(const float* __restrict__ diffs, const unsigned* __restrict__ meta,
                        unsigned* __restrict__ h2) {
  int p = blockIdx.x * 256 + threadIdx.x;
  if (p >= NPOS) return;
  unsigned key = __float_as_uint(diffs[p]);
  if ((key >> 16) == meta[0]) atomicAdd(&h2[key & 0xffffu], 1u);
}

__global__ void k_sel_lo(const unsigned* __restrict__ h2, unsigned* __restrict__ meta) {
  __shared__ unsigned loc[256];
  int t = threadIdx.x;
  unsigned s = 0;
  for (int i = 0; i < 256; ++i) s += h2[t * 256 + i];
  loc[t] = s;
  __syncthreads();
  if (t == 0) {
    unsigned remaining = KSEL - meta[1];
    unsigned run = 0; int tt = 255;
    for (; tt > 0; --tt) { if (run + loc[tt] >= remaining) break; run += loc[tt]; }
    unsigned r2 = run;
    for (int i = 255; i >= 0; --i) {
      unsigned c = h2[tt * 256 + i];
      if (r2 + c >= remaining) {
        meta[2] = (meta[0] << 16) | (unsigned)(tt * 256 + i);
        meta[3] = remaining - r2;
        break;
      }
      r2 += c;
    }
  }
}

// --------------------------- D: keep flags ---------------------------------
__global__ __launch_bounds__(64) void k_keep(const float* __restrict__ diffs,
                                             const unsigned* __restrict__ meta,
                                             unsigned char* __restrict__ keep) {
  int lane = threadIdx.x;
  unsigned Kstar = meta[2], need = meta[3];
  unsigned base = 0;
  float v[4], nv[4];
#pragma unroll
  for (int q = 0; q < 4; ++q) nv[q] = diffs[q * 64 + lane];
  for (int it = 0; it < 257; ++it) {
#pragma unroll
    for (int q = 0; q < 4; ++q) v[q] = nv[q];
    if (it < 256) {
      int nb = (it + 1) * 256;
#pragma unroll
      for (int q = 0; q < 4; ++q) {
        int idx = nb + q * 64 + lane;
        nv[q] = (idx < NPOS) ? diffs[idx] : 0.f;
      }
    }
#pragma unroll
    for (int q = 0; q < 4; ++q) {
      int p = it * 256 + q * 64 + lane;
      bool valid = p < NPOS;
      unsigned key = valid ? __float_as_uint(v[q]) : 0u;
      bool eq = valid && (key == Kstar);
      unsigned long long m = __ballot(eq);
      unsigned rank = base + (unsigned)__popcll(m & ((1ull << lane) - 1ull));
      bool k = valid && ((key > Kstar) || (eq && rank < need) || ((p & 1023) == 0));
      if (valid) keep[p] = (unsigned char)k;
      base += (unsigned)__popcll(m);
    }
  }
}

// --------------------------- E: per-batch segments -------------------------
__global__ __launch_bounds__(1024) void k_segment(const unsigned char* __restrict__ keep,
                                                  int* __restrict__ segid,
                                                  int* __restrict__ bnd,
                                                  int* __restrict__ nseg) {
  __shared__ int s[1024];
  int b = blockIdx.x, t = threadIdx.x;
  int f = (t >= 1) ? (int)keep[b * 1024 + t] : 0;
  s[t] = f;
  __syncthreads();
  for (int off = 1; off < 1024; off <<= 1) {
    int v = s[t];
    int add = (t >= off) ? s[t - off] : 0;
    __syncthreads();
    s[t] = v + add;
    __syncthreads();
  }
  int sc = s[t];
  segid[b * 1024 + t] = sc;
  if (f) bnd[b * 1026 + sc] = t;
  if (t == 0) bnd[b * 1026] = 0;
  if (t == 1023) {
    int m = sc + 1;
    nseg[b] = m;
    bnd[b * 1026 + m] = 1024;
  }
}

__global__ __launch_bounds__(64) void k_prefix(const int* __restrict__ nseg,
                                               int* __restrict__ pref) {
  int lane = threadIdx.x;
  int s = nseg[lane];
  for (int off = 1; off < 64; off <<= 1) {
    int u = __shfl_up(s, off);
    if (lane >= off) s += u;
  }
  pref[lane + 1] = s;
  if (lane == 0) pref[0] = 0;
}

// --------------------------- G: segment means ------------------------------
__global__ __launch_bounds__(256) void k_pool(const float* __restrict__ x,
                                              const int* __restrict__ bnd,
                                              const int* __restrict__ nseg,
                                              const int* __restrict__ pref,
                                              float* __restrict__ comp) {
  int d = threadIdx.x;
  for (int s = 0; s < 32; ++s) {
    int sid = blockIdx.x * 32 + s;
    int b = sid >> 10, li = sid & 1023;
    if (li >= nseg[b]) continue;
    int s0 = bnd[b * 1026 + li], e0 = bnd[b * 1026 + li + 1];
    float acc = 0.f;
    for (int t = s0; t < e0; ++t) acc += x[((size_t)b * 1024 + t) * 256 + d];
    comp[((size_t)pref[b] + li) * 256 + d] = acc / (float)(e0 - s0);
  }
}

// --------------------------- H: gi GEMM (fp32) -----------------------------
__global__ __launch_bounds__(256) void k_gi(const float* __restrict__ comp,
                                            const float* __restrict__ Wih,
                                            const float* __restrict__ bih,
                                            const float* __restrict__ bhh,
                                            const int* __restrict__ pref,
                                            float* __restrict__ gi) {
  int total = pref[64];
  int r0 = blockIdx.x * 64;
  if (r0 >= total) return;
  int c0 = blockIdx.y * 128;
  __shared__ float As[64][64];
  __shared__ float Bs[64 * 132];
  int tid = threadIdx.x;
  int rg = tid >> 5, cl = tid & 31;
  float acc[8][4];
#pragma unroll
  for (int i = 0; i < 8; ++i)
#pragma unroll
    for (int q = 0; q < 4; ++q) acc[i][q] = 0.f;

  for (int k0 = 0; k0 < 256; k0 += 64) {
#pragma unroll
    for (int i = 0; i < 4; ++i) {
      int idx = tid + i * 256;
      int row = idx >> 4, kq = idx & 15;
      int rr = r0 + row;
      float4 v;
      if (rr < total) v = *reinterpret_cast<const float4*>(comp + (size_t)rr * 256 + k0 + kq * 4);
      else { v.x = 0.f; v.y = 0.f; v.z = 0.f; v.w = 0.f; }
      *reinterpret_cast<float4*>(&As[row][kq * 4]) = v;
    }
#pragma unroll
    for (int i = 0; i < 8; ++i) {
      int idx = tid + i * 256;
      int row = idx >> 4, kq = idx & 15;
      float4 v = *reinterpret_cast<const float4*>(Wih + (size_t)(c0 + row) * 256 + k0 + kq * 4);
      Bs[(kq * 4 + 0) * 132 + row] = v.x;
      Bs[(kq * 4 + 1) * 132 + row] = v.y;
      Bs[(kq * 4 + 2) * 132 + row] = v.z;
      Bs[(kq * 4 + 3) * 132 + row] = v.w;
    }
    __syncthreads();
#pragma unroll 4
    for (int k = 0; k < 64; ++k) {
      float a[8], bv[4];
#pragma unroll
      for (int i = 0; i < 8; ++i) a[i] = As[rg * 8 + i][k];
#pragma unroll
      for (int q = 0; q < 4; ++q) bv[q] = Bs[k * 132 + cl + 32 * q];
#pragma unroll
      for (int i = 0; i < 8; ++i)
#pragma unroll
        for (int q = 0; q < 4; ++q) acc[i][q] += a[i] * bv[q];
    }
    __syncthreads();
  }
#pragma unroll
  for (int q = 0; q < 4; ++q) {
    int c = c0 + cl + 32 * q;
    float bias = bih[c] + (c < 512 ? bhh[c] : 0.f);
#pragma unroll
    for (int i = 0; i < 8; ++i) {
      int rr = r0 + rg * 8 + i;
      if (rr < total) gi[(size_t)rr * 768 + c] = acc[i][q] + bias;
    }
  }
}

// --------------------------- I: GRU ----------------------------------------
__global__ __launch_bounds__(512, 2) void k_gru(const float* __restrict__ gi,
                                                const float* __restrict__ Whh,
                                                const float* __restrict__ bhh,
                                                const int* __restrict__ nseg,
                                                const int* __restrict__ pref,
                                                float* __restrict__ gout) {
  int b = blockIdx.x;
  int t = threadIdx.x;
  int m = nseg[b];
  size_t base = (size_t)pref[b];

  f16x2 wf[128];
#pragma unroll
  for (int i = 0; i < 64; ++i) {
    float4 v = *reinterpret_cast<const float4*>(Whh + (size_t)t * 256 + i * 4);
    f16x2 lo; lo.x = (_Float16)v.x; lo.y = (_Float16)v.y;
    f16x2 hi; hi.x = (_Float16)v.z; hi.y = (_Float16)v.w;
    wf[2 * i] = lo; wf[2 * i + 1] = hi;
  }
  int nrow = 512 + (t >> 1);
  int koff = (t & 1) * 128;
  f16x2 wh[64];
#pragma unroll
  for (int i = 0; i < 32; ++i) {
    float4 v = *reinterpret_cast<const float4*>(Whh + (size_t)nrow * 256 + koff + i * 4);
    f16x2 lo; lo.x = (_Float16)v.x; lo.y = (_Float16)v.y;
    f16x2 hi; hi.x = (_Float16)v.z; hi.y = (_Float16)v.w;
    wh[2 * i] = lo; wh[2 * i + 1] = hi;
  }

  __shared__ f16x2 h2buf[128];
  __shared__ float hf[256];
  __shared__ float sg[512];
  __shared__ float pn[512];

  float bn = (t < 256) ? bhh[512 + t] : 0.f;
  if (t < 128) ((unsigned*)h2buf)[t] = 0u;
  if (t < 256) hf[t] = 0.f;
  __syncthreads();

  int hb = koff >> 1;

  for (int l = 0; l < m; ++l) {
    const float* girow = gi + (base + l) * 768;
    float gv = girow[t];
    float gn = (t < 256) ? girow[512 + t] : 0.f;

    float af0 = 0.f, af1 = 0.f;
#pragma unroll
    for (int i = 0; i < 64; ++i) {
      af0 = fdot2f(wf[2 * i],     h2buf[2 * i],     af0);
      af1 = fdot2f(wf[2 * i + 1], h2buf[2 * i + 1], af1);
    }
    float af = af0 + af1;
    float ah0 = 0.f, ah1 = 0.f;
#pragma unroll
    for (int i = 0; i < 32; ++i) {
      ah0 = fdot2f(wh[2 * i],     h2buf[hb + 2 * i],     ah0);
      ah1 = fdot2f(wh[2 * i + 1], h2buf[hb + 2 * i + 1], ah1);
    }
    float ah = ah0 + ah1;

    sg[t] = 1.f / (1.f + expf(-(gv + af)));
    pn[t] = ah;
    __syncthreads();
    if (t < 256) {
      float r = sg[t], z = sg[256 + t];
      float hn = pn[2 * t] + pn[2 * t + 1] + bn;
      float n = tanhf(gn + r * hn);
      float hnew = (1.f - z) * n + z * hf[t];
      hf[t] = hnew;
      ((_Float16*)h2buf)[t] = (_Float16)hnew;
      gout[(base + l) * 256 + t] = hnew;
    }
    __syncthreads();
  }
}

// --------------------------- J: scatter ------------------------------------
__global__ __launch_bounds__(256) void k_scatter(const float* __restrict__ gout,
                                                 const int* __restrict__ segid,
                                                 const int* __restrict__ pref,
                                                 float* __restrict__ out) {
  int d = threadIdx.x;
  for (int rr = 0; rr < 32; ++rr) {
    int row = blockIdx.x * 32 + rr;
    int b = row >> 10;
    int l = segid[row];
    out[(size_t)row * 256 + d] = gout[((size_t)pref[b] + l) * 256 + d];
  }
}

// ---------------------------------------------------------------------------
extern "C" void kernel_launch(void* const* d_in, const int* in_sizes, int n_in,
                              void* d_out, int out_size, void* d_ws, size_t ws_size,
                              hipStream_t stream) {
  const float* x   = (const float*)d_in[0];
  const float* Wih = (const float*)d_in[1];
  const float* Whh = (const float*)d_in[2];
  const float* bih = (const float*)d_in[3];
  const float* bhh = (const float*)d_in[4];
  float* out = (float*)d_out;
  char* w = (char*)d_ws;

  const size_t o_cs1   = 0;
  const size_t o_cs2   = 67110912;
  const size_t o_diffs = 134221824;
  const size_t o_h1    = 134484224;
  const size_t o_h2    = 134746368;
  const size_t o_meta  = 135008512;
  const size_t o_keep  = 135008768;
  const size_t o_segid = 135074560;
  const size_t o_bnd   = 135336704;
  const size_t o_nseg  = 135599360;
  const size_t o_pref  = 135599616;
  const size_t o_gi    = 135600128;
  const size_t NEED    = 236460032;
  if (ws_size < NEED) return;

  float* cs1 = (float*)(w + o_cs1);
  float* cs2 = (float*)(w + o_cs2);
  float* diffs = (float*)(w + o_diffs);
  unsigned* h1 = (unsigned*)(w + o_h1);
  unsigned* h2 = (unsigned*)(w + o_h2);
  unsigned* meta = (unsigned*)(w + o_meta);
  unsigned char* keep = (unsigned char*)(w + o_keep);
  int* segid = (int*)(w + o_segid);
  int* bnd = (int*)(w + o_bnd);
  int* nseg = (int*)(w + o_nseg);
  int* pref = (int*)(w + o_pref);
  float* gi = (float*)(w + o_gi);
  float* comp = cs1;  // reuse
  float* gout = cs2;  // reuse
  float* sink = (float*)(w + o_meta + 192);

  hipMemsetAsync(h1, 0, 262144, stream);
  hipMemsetAsync(h2, 0, 262144, stream);

  k_warm   <<<dim3(16384),  dim3(256),  0, stream>>>((const float4*)x, sink);
  k_chain  <<<dim3(8),      dim3(256),  0, stream>>>(x, cs1, cs2);
  k_diffs  <<<dim3(1025),   dim3(64),   0, stream>>>(cs1, cs2, diffs);
  k_hist1  <<<dim3(257),    dim3(256),  0, stream>>>(diffs, h1);
  k_sel_hi <<<dim3(1),      dim3(256),  0, stream>>>(h1, meta);
  k_hist2  <<<dim3(257),    dim3(256),  0, stream>>>(diffs, meta, h2);
  k_sel_lo <<<dim3(1),      dim3(256),  0, stream>>>(h2, meta);
  k_keep   <<<dim3(1),      dim3(64),   0, stream>>>(diffs, meta, keep);
  k_segment<<<dim3(64),     dim3(1024), 0, stream>>>(keep, segid, bnd, nseg);
  k_prefix <<<dim3(1),      dim3(64),   0, stream>>>(nseg, pref);
  k_pool   <<<dim3(2048),   dim3(256),  0, stream>>>(x, bnd, nseg, pref, comp);
  k_gi     <<<dim3(513, 6), dim3(256),  0, stream>>>(comp, Wih, bih, bhh, pref, gi);
  k_gru    <<<dim3(64),     dim3(512),  0, stream>>>(gi, Whh, bhh, nseg, pref, gout);
  k_scatter<<<dim3(2048),   dim3(256),  0, stream>>>(gout, segid, pref, out);
}

// Round 5
// 2260.386 us; speedup vs baseline: 3.5011x; 1.1289x over previous
//
#include <hip/hip_runtime.h>
#include <cstdint>
#include <cstddef>
#include <cmath>

// ---------------------------------------------------------------------------
// Pipeline:
//   A0 k_warm   : pull x into L2/L3 (full-GPU streaming read, ~13us)
//   A1 k_carry  : exact sequential fl cumsum chains (8 blocks, loads-only
//                 FIFO, register pipeline) writing 256-row checkpoints only
//   A2 k_spread : 512 blocks replay each 256-row chunk from its exact carry
//                 (identical rounding sequence -> bit-exact), coalesced IO
//   B  k_diffs  : exact numpy-pairwise variance->diffs (float4 loads)
//   C  k_hist1/k_sel_hi/k_hist2/k_sel_lo : exact top-32768 radix select
//   D  k_keep   : keep flags, stable tie ranks
//   E  k_segment: per-batch boundary lists + frame->segment map
//   F  k_prefix : ragged row offsets
//   G  k_pool   : segment means (comp)
//   H  k_gi     : gi = comp @ W_ih^T + biases  [fp32 GEMM]
//   I  k_gru    : sequential GRU, 768 thr/block, k-half split W in VGPRs,
//                 uniform b128 h reads, raw-barrier sync, gi prefetch
//   J  k_scatter: out[b,t,:] = gru_out[b, seg(t), :]
// ---------------------------------------------------------------------------

#define NPOS 65537
#define KSEL 32768u

typedef _Float16 f16x2 __attribute__((ext_vector_type(2)));
typedef _Float16 f16x8 __attribute__((ext_vector_type(8)));

#if defined(__has_builtin)
#if __has_builtin(__builtin_amdgcn_fdot2)
#define HAVE_FDOT2 1
#endif
#endif

__device__ __forceinline__ float fdot2f(f16x2 a, f16x2 b, float c) {
#ifdef HAVE_FDOT2
  return __builtin_amdgcn_fdot2(a, b, c, false);
#else
  c += (float)a.x * (float)b.x;
  c += (float)a.y * (float)b.y;
  return c;
#endif
}

// --------------------------- A0: warm x into cache -------------------------
__global__ __launch_bounds__(256) void k_warm(const float4* __restrict__ x4,
                                              float* __restrict__ sink) {
  size_t i = (size_t)blockIdx.x * 256 + threadIdx.x;
  float4 v = x4[i];
  float s = (v.x + v.y) + (v.z + v.w);
  if (s == 1.23456789e-33f) sink[0] = s;  // deterministically false; keeps loads
}

// --------------------------- A1: carry chains ------------------------------
// 8 blocks x 64 lanes. Block b: SQ=b>>2 (plain vs squared), cols
// j0=(b&3)*64; lane l owns column j0+l, serial fl-chain over 65536 rows.
// Writes ONLY the chain value at every 256-row boundary (carr[chunk][col]);
// the VMEM FIFO is loads-only (48 dwords in flight, D=4 x U=16 rotation).
template<bool SQ>
__device__ __forceinline__ void carry_run(const float* __restrict__ src,
                                          float* __restrict__ carr, int j0) {
#pragma clang fp contract(off)
  const int l = threadIdx.x;
  const float* gp = src + j0 + l;
  float* cw = carr + j0 + l;
  float buf[4][16];
#pragma unroll
  for (int d = 0; d < 3; ++d)
#pragma unroll
    for (int u = 0; u < 16; ++u)
      buf[d][u] = gp[(size_t)(d * 16 + u) * 256];
  float c = 0.f;
  for (int g = 0; g < 1024; ++g) {
#pragma unroll
    for (int d = 0; d < 4; ++d) {
      const int s = g * 4 + d;          // 16-row group index (0..4095)
      if (d == 0 && (g & 3) == 0)
        cw[(size_t)(g >> 2) * 256] = c; // carry BEFORE rows of chunk g>>2
      if (s + 3 < 4096) {
        const float* ld = gp + (size_t)(s + 3) * 16 * 256;
#pragma unroll
        for (int u = 0; u < 16; ++u)
          buf[(d + 3) & 3][u] = ld[(size_t)u * 256];
      }
#pragma unroll
      for (int u = 0; u < 16; ++u) {
        float v = buf[d][u];
        if (SQ) v = v * v;              // rounded square, then add (no FMA)
        c = c + v;
      }
    }
  }
}

__global__ __launch_bounds__(64) void k_carry(const float* __restrict__ x,
                                              float* __restrict__ carr) {
  const int sq = blockIdx.x >> 2;
  const int j0 = (blockIdx.x & 3) * 64;
  if (sq) carry_run<true>(x, carr + 65536, j0);
  else    carry_run<false>(x, carr, j0);
}

// --------------------------- A2: spread chunks -----------------------------
// 512 blocks x 256 threads: block = (sq, chunk). Replays the 256-row chain
// of its chunk starting from the exact carry -> bit-identical fl sequence.
// Coalesced 1KB row loads/stores; D=4 x U=8 register pipeline.
__global__ __launch_bounds__(256) void k_spread(const float* __restrict__ x,
                                                const float* __restrict__ carr,
                                                float* __restrict__ cs1,
                                                float* __restrict__ cs2) {
#pragma clang fp contract(off)
  const int blk = blockIdx.x;
  const int sq = blk >> 8;
  const int ch = blk & 255;
  const int col = threadIdx.x;
  float* dst = sq ? cs2 : cs1;
  float c = carr[((size_t)sq * 256 + ch) * 256 + col];
  const float* gp = x + (size_t)ch * 256 * 256 + col;
  float* sp = dst + ((size_t)ch * 256 + 1) * 256 + col;
  if (ch == 0) dst[col] = 0.f;        // p=0 row (enc zero prepend)
  float buf[4][8];
#pragma unroll
  for (int d = 0; d < 3; ++d)
#pragma unroll
    for (int u = 0; u < 8; ++u)
      buf[d][u] = gp[(size_t)(d * 8 + u) * 256];
  for (int g = 0; g < 8; ++g) {
#pragma unroll
    for (int d = 0; d < 4; ++d) {
      const int s = g * 4 + d;        // 8-row group (0..31)
      if (s + 3 < 32) {
        const float* ld = gp + (size_t)(s + 3) * 8 * 256;
#pragma unroll
        for (int u = 0; u < 8; ++u)
          buf[(d + 3) & 3][u] = ld[(size_t)u * 256];
      }
#pragma unroll
      for (int u = 0; u < 8; ++u) {
        float v = buf[d][u];
        if (sq) v = v * v;
        c = c + v;
        sp[(size_t)(s * 8 + u) * 256] = c;
      }
    }
  }
}

// --------------------------- B: exact diffs --------------------------------
// Same op order as numpy: s1/2, s2/2, pairwise mean (two 128-blocks,
// 8 accumulators, specific combine), sqrt via double. float4 loads.
__device__ __forceinline__ float dterm(float ap, float am, float bp, float bm) {
#pragma clang fp contract(off)
  float s1 = ap - am;
  float s2 = bp - bm;
  float t1 = s1 * 0.5f;
  float u = s2 * 0.5f;
  return u - t1 * t1;
}

__global__ __launch_bounds__(64) void k_diffs(const float* __restrict__ cs1,
                                              const float* __restrict__ cs2,
                                              float* __restrict__ diffs) {
#pragma clang fp contract(off)
  int p = blockIdx.x * 64 + threadIdx.x;
  if (p >= NPOS) return;
  if (p == 0 || p == NPOS - 1) { diffs[p] = 1e10f; return; }
  const float4* am4 = (const float4*)(cs1 + (size_t)(p - 1) * 256);
  const float4* ap4 = (const float4*)(cs1 + (size_t)(p + 1) * 256);
  const float4* bm4 = (const float4*)(cs2 + (size_t)(p - 1) * 256);
  const float4* bp4 = (const float4*)(cs2 + (size_t)(p + 1) * 256);
  float blk[2];
  for (int half = 0; half < 2; ++half) {
    float r[8];
    for (int i = 0; i < 16; ++i) {
      int q = half * 32 + i * 2;
      float4 a0 = ap4[q], m0 = am4[q], b0 = bp4[q], n0 = bm4[q];
      float4 a1 = ap4[q + 1], m1 = am4[q + 1], b1 = bp4[q + 1], n1 = bm4[q + 1];
      float e0 = dterm(a0.x, m0.x, b0.x, n0.x);
      float e1 = dterm(a0.y, m0.y, b0.y, n0.y);
      float e2 = dterm(a0.z, m0.z, b0.z, n0.z);
      float e3 = dterm(a0.w, m0.w, b0.w, n0.w);
      float e4 = dterm(a1.x, m1.x, b1.x, n1.x);
      float e5 = dterm(a1.y, m1.y, b1.y, n1.y);
      float e6 = dterm(a1.z, m1.z, b1.z, n1.z);
      float e7 = dterm(a1.w, m1.w, b1.w, n1.w);
      if (i == 0) {
        r[0] = e0; r[1] = e1; r[2] = e2; r[3] = e3;
        r[4] = e4; r[5] = e5; r[6] = e6; r[7] = e7;
      } else {
        r[0] += e0; r[1] += e1; r[2] += e2; r[3] += e3;
        r[4] += e4; r[5] += e5; r[6] += e6; r[7] += e7;
      }
    }
    blk[half] = ((r[0] + r[1]) + (r[2] + r[3])) + ((r[4] + r[5]) + (r[6] + r[7]));
  }
  float mean = (blk[0] + blk[1]) / 256.0f;
  float mx = mean > 0.0f ? mean : 0.0f;
  diffs[p] = (float)::sqrt((double)mx);
}

// --------------------------- C: radix select -------------------------------
__global__ void k_hist1(const float* __restrict__ diffs, unsigned* __restrict__ h1) {
  int p = blockIdx.x * 256 + threadIdx.x;
  if (p >= NPOS) return;
  unsigned key = __float_as_uint(diffs[p]);
  atomicAdd(&h1[key >> 16], 1u);
}

__global__ void k_sel_hi(const unsigned* __restrict__ h1, unsigned* __restrict__ meta) {
  __shared__ unsigned loc[256];
  int t = threadIdx.x;
  unsigned s = 0;
  for (int i = 0; i < 256; ++i) s += h1[t * 256 + i];
  loc[t] = s;
  __syncthreads();
  if (t == 0) {
    unsigned run = 0; int tt = 255;
    for (; tt > 0; --tt) { if (run + loc[tt] >= KSEL) break; run += loc[tt]; }
    unsigned r2 = run;
    for (int i = 255; i >= 0; --i) {
      unsigned c = h1[tt * 256 + i];
      if (r2 + c >= KSEL) { meta[0] = (unsigned)(tt * 256 + i); meta[1] = r2; break; }
      r2 += c;
    }
  }
}

__global__ void k_hist2(const float* __restrict__ diffs, const unsigned* __restrict__ meta,
                        unsigned* __restrict__ h2) {
  int p = blockIdx.x * 256 + threadIdx.x;
  if (p >= NPOS) return;
  unsigned key = __float_as_uint(diffs[p]);
  if ((key >> 16) == meta[0]) atomicAdd(&h2[key & 0xffffu], 1u);
}

__global__ void k_sel_lo(const unsigned* __restrict__ h2, unsigned* __restrict__ meta) {
  __shared__ unsigned loc[256];
  int t = threadIdx.x;
  unsigned s = 0;
  for (int i = 0; i < 256; ++i) s += h2[t * 256 + i];
  loc[t] = s;
  __syncthreads();
  if (t == 0) {
    unsigned remaining = KSEL - meta[1];
    unsigned run = 0; int tt = 255;
    for (; tt > 0; --tt) { if (run + loc[tt] >= remaining) break; run += loc[tt]; }
    unsigned r2 = run;
    for (int i = 255; i >= 0; --i) {
      unsigned c = h2[tt * 256 + i];
      if (r2 + c >= remaining) {
        meta[2] = (meta[0] << 16) | (unsigned)(tt * 256 + i);
        meta[3] = remaining - r2;
        break;
      }
      r2 += c;
    }
  }
}

// --------------------------- D: keep flags ---------------------------------
__global__ __launch_bounds__(64) void k_keep(const float* __restrict__ diffs,
                                             const unsigned* __restrict__ meta,
                                             unsigned char* __restrict__ keep) {
  int lane = threadIdx.x;
  unsigned Kstar = meta[2], need = meta[3];
  unsigned base = 0;
  float v[4], nv[4];
#pragma unroll
  for (int q = 0; q < 4; ++q) nv[q] = diffs[q * 64 + lane];
  for (int it = 0; it < 257; ++it) {
#pragma unroll
    for (int q = 0; q < 4; ++q) v[q] = nv[q];
    if (it < 256) {
      int nb = (it + 1) * 256;
#pragma unroll
      for (int q = 0; q < 4; ++q) {
        int idx = nb + q * 64 + lane;
        nv[q] = (idx < NPOS) ? diffs[idx] : 0.f;
      }
    }
#pragma unroll
    for (int q = 0; q < 4; ++q) {
      int p = it * 256 + q * 64 + lane;
      bool valid = p < NPOS;
      unsigned key = valid ? __float_as_uint(v[q]) : 0u;
      bool eq = valid && (key == Kstar);
      unsigned long long m = __ballot(eq);
      unsigned rank = base + (unsigned)__popcll(m & ((1ull << lane) - 1ull));
      bool k = valid && ((key > Kstar) || (eq && rank < need) || ((p & 1023) == 0));
      if (valid) keep[p] = (unsigned char)k;
      base += (unsigned)__popcll(m);
    }
  }
}

// --------------------------- E: per-batch segments -------------------------
__global__ __launch_bounds__(1024) void k_segment(const unsigned char* __restrict__ keep,
                                                  int* __restrict__ segid,
                                                  int* __restrict__ bnd,
                                                  int* __restrict__ nseg) {
  __shared__ int s[1024];
  int b = blockIdx.x, t = threadIdx.x;
  int f = (t >= 1) ? (int)keep[b * 1024 + t] : 0;
  s[t] = f;
  __syncthreads();
  for (int off = 1; off < 1024; off <<= 1) {
    int v = s[t];
    int add = (t >= off) ? s[t - off] : 0;
    __syncthreads();
    s[t] = v + add;
    __syncthreads();
  }
  int sc = s[t];
  segid[b * 1024 + t] = sc;
  if (f) bnd[b * 1026 + sc] = t;
  if (t == 0) bnd[b * 1026] = 0;
  if (t == 1023) {
    int m = sc + 1;
    nseg[b] = m;
    bnd[b * 1026 + m] = 1024;
  }
}

__global__ __launch_bounds__(64) void k_prefix(const int* __restrict__ nseg,
                                               int* __restrict__ pref) {
  int lane = threadIdx.x;
  int s = nseg[lane];
  for (int off = 1; off < 64; off <<= 1) {
    int u = __shfl_up(s, off);
    if (lane >= off) s += u;
  }
  pref[lane + 1] = s;
  if (lane == 0) pref[0] = 0;
}

// --------------------------- G: segment means ------------------------------
__global__ __launch_bounds__(256) void k_pool(const float* __restrict__ x,
                                              const int* __restrict__ bnd,
                                              const int* __restrict__ nseg,
                                              const int* __restrict__ pref,
                                              float* __restrict__ comp) {
  int d = threadIdx.x;
  for (int s = 0; s < 32; ++s) {
    int sid = blockIdx.x * 32 + s;
    int b = sid >> 10, li = sid & 1023;
    if (li >= nseg[b]) continue;
    int s0 = bnd[b * 1026 + li], e0 = bnd[b * 1026 + li + 1];
    float acc = 0.f;
    for (int t = s0; t < e0; ++t) acc += x[((size_t)b * 1024 + t) * 256 + d];
    comp[((size_t)pref[b] + li) * 256 + d] = acc / (float)(e0 - s0);
  }
}

// --------------------------- H: gi GEMM (fp32) -----------------------------
__global__ __launch_bounds__(256) void k_gi(const float* __restrict__ comp,
                                            const float* __restrict__ Wih,
                                            const float* __restrict__ bih,
                                            const float* __restrict__ bhh,
                                            const int* __restrict__ pref,
                                            float* __restrict__ gi) {
  int total = pref[64];
  int r0 = blockIdx.x * 64;
  if (r0 >= total) return;
  int c0 = blockIdx.y * 128;
  __shared__ float As[64][64];
  __shared__ float Bs[64 * 132];
  int tid = threadIdx.x;
  int rg = tid >> 5, cl = tid & 31;
  float acc[8][4];
#pragma unroll
  for (int i = 0; i < 8; ++i)
#pragma unroll
    for (int q = 0; q < 4; ++q) acc[i][q] = 0.f;

  for (int k0 = 0; k0 < 256; k0 += 64) {
#pragma unroll
    for (int i = 0; i < 4; ++i) {
      int idx = tid + i * 256;
      int row = idx >> 4, kq = idx & 15;
      int rr = r0 + row;
      float4 v;
      if (rr < total) v = *reinterpret_cast<const float4*>(comp + (size_t)rr * 256 + k0 + kq * 4);
      else { v.x = 0.f; v.y = 0.f; v.z = 0.f; v.w = 0.f; }
      *reinterpret_cast<float4*>(&As[row][kq * 4]) = v;
    }
#pragma unroll
    for (int i = 0; i < 8; ++i) {
      int idx = tid + i * 256;
      int row = idx >> 4, kq = idx & 15;
      float4 v = *reinterpret_cast<const float4*>(Wih + (size_t)(c0 + row) * 256 + k0 + kq * 4);
      Bs[(kq * 4 + 0) * 132 + row] = v.x;
      Bs[(kq * 4 + 1) * 132 + row] = v.y;
      Bs[(kq * 4 + 2) * 132 + row] = v.z;
      Bs[(kq * 4 + 3) * 132 + row] = v.w;
    }
    __syncthreads();
#pragma unroll 4
    for (int k = 0; k < 64; ++k) {
      float a[8], bv[4];
#pragma unroll
      for (int i = 0; i < 8; ++i) a[i] = As[rg * 8 + i][k];
#pragma unroll
      for (int q = 0; q < 4; ++q) bv[q] = Bs[k * 132 + cl + 32 * q];
#pragma unroll
      for (int i = 0; i < 8; ++i)
#pragma unroll
        for (int q = 0; q < 4; ++q) acc[i][q] += a[i] * bv[q];
    }
    __syncthreads();
  }
#pragma unroll
  for (int q = 0; q < 4; ++q) {
    int c = c0 + cl + 32 * q;
    float bias = bih[c] + (c < 512 ? bhh[c] : 0.f);
#pragma unroll
    for (int i = 0; i < 8; ++i) {
      int rr = r0 + rg * 8 + i;
      if (rr < total) gi[(size_t)rr * 768 + c] = acc[i][q] + bias;
    }
  }
}

// --------------------------- I: GRU ----------------------------------------
// 64 blocks x 768 threads (12 waves, 3/SIMD). Thread (pr, half) owns rows
// {pr, 384+pr} restricted to k-half `half` (2 x 64 f16x2 = 128 VGPRs).
// h (f16) read as wave-uniform ds_read_b128 (16/wave/step). Partials
// combined via LDS float2. Raw s_barrier sync (no vmcnt drain) so gout
// stores + next-step gi prefetch stay in flight.
__global__ __launch_bounds__(768, 3) void k_gru(const float* __restrict__ gi,
                                                const float* __restrict__ Whh,
                                                const float* __restrict__ bhh,
                                                const int* __restrict__ nseg,
                                                const int* __restrict__ pref,
                                                float* __restrict__ gout) {
  const int b = blockIdx.x;
  const int t = threadIdx.x;
  const int m = nseg[b];
  const size_t base = (size_t)pref[b];
  const int half = (t >= 384) ? 1 : 0;     // wave-uniform (waves 0-5 / 6-11)
  const int pr = t - half * 384;           // 0..383
  const int row0 = pr, row1 = 384 + pr;
  const int k0 = half * 128;

  f16x2 w0[64], w1[64];
#pragma unroll
  for (int i = 0; i < 32; ++i) {
    float4 v = *(const float4*)(Whh + (size_t)row0 * 256 + k0 + i * 4);
    f16x2 aa; aa.x = (_Float16)v.x; aa.y = (_Float16)v.y; w0[2 * i] = aa;
    f16x2 ab; ab.x = (_Float16)v.z; ab.y = (_Float16)v.w; w0[2 * i + 1] = ab;
    float4 u = *(const float4*)(Whh + (size_t)row1 * 256 + k0 + i * 4);
    f16x2 ba; ba.x = (_Float16)u.x; ba.y = (_Float16)u.y; w1[2 * i] = ba;
    f16x2 bb; bb.x = (_Float16)u.z; bb.y = (_Float16)u.w; w1[2 * i + 1] = bb;
  }

  __shared__ f16x8 hbuf8[32];     // h as f16 (256 vals); [half*16+i] uniform
  __shared__ float2 pp2[768];     // per-row {half0, half1} partials

  float bn = (t < 256) ? bhh[512 + t] : 0.f;
  float hreg = 0.f;               // finish thread t<256 owns h[t] in f32
  if (t < 64) {
    f16x8 z = (f16x8)(_Float16)0.f;
    if (t < 32) hbuf8[t] = z;
  }
  __syncthreads();

  float cr = 0.f, cz = 0.f, cn = 0.f;
  if (t < 256) {
    const float* g0 = gi + base * 768;
    cr = g0[t]; cz = g0[256 + t]; cn = g0[512 + t];
  }

  for (int l = 0; l < m; ++l) {
    float nr = 0.f, nz = 0.f, nn = 0.f;
    if (t < 256 && l + 1 < m) {            // prefetch next step's gi
      const float* g1 = gi + (base + l + 1) * 768;
      nr = g1[t]; nz = g1[256 + t]; nn = g1[512 + t];
    }
    float a0 = 0.f, a1 = 0.f, a2 = 0.f, a3 = 0.f;
#pragma unroll
    for (int i = 0; i < 16; ++i) {
      f16x8 hv = hbuf8[half * 16 + i];     // uniform ds_read_b128
      f16x2 p0; p0.x = hv[0]; p0.y = hv[1];
      f16x2 p1; p1.x = hv[2]; p1.y = hv[3];
      f16x2 p2; p2.x = hv[4]; p2.y = hv[5];
      f16x2 p3; p3.x = hv[6]; p3.y = hv[7];
      a0 = fdot2f(w0[4 * i + 0], p0, a0);
      a2 = fdot2f(w0[4 * i + 1], p1, a2);
      a0 = fdot2f(w0[4 * i + 2], p2, a0);
      a2 = fdot2f(w0[4 * i + 3], p3, a2);
      a1 = fdot2f(w1[4 * i + 0], p0, a1);
      a3 = fdot2f(w1[4 * i + 1], p1, a3);
      a1 = fdot2f(w1[4 * i + 2], p2, a1);
      a3 = fdot2f(w1[4 * i + 3], p3, a3);
    }
    float* ppf = (float*)pp2;
    ppf[row0 * 2 + half] = a0 + a2;
    ppf[row1 * 2 + half] = a1 + a3;
    asm volatile("s_waitcnt lgkmcnt(0)" ::: "memory");
    __builtin_amdgcn_sched_barrier(0);
    __builtin_amdgcn_s_barrier();
    __builtin_amdgcn_sched_barrier(0);
    if (t < 256) {
      float2 qr = pp2[t];
      float2 qz = pp2[256 + t];
      float2 qn = pp2[512 + t];
      float sr = qr.x + qr.y;
      float sz = qz.x + qz.y;
      float sn = qn.x + qn.y + bn;
      float r = 1.f / (1.f + __expf(-(cr + sr)));
      float z = 1.f / (1.f + __expf(-(cz + sz)));
      float arg = cn + r * sn;
      float n = 2.f / (1.f + __expf(-2.f * arg)) - 1.f;   // tanh
      float hnew = (1.f - z) * n + z * hreg;
      hreg = hnew;
      ((_Float16*)hbuf8)[t] = (_Float16)hnew;
      gout[(base + l) * 256 + t] = hnew;
    }
    cr = nr; cz = nz; cn = nn;
    asm volatile("s_waitcnt lgkmcnt(0)" ::: "memory");
    __builtin_amdgcn_sched_barrier(0);
    __builtin_amdgcn_s_barrier();
    __builtin_amdgcn_sched_barrier(0);
  }
}

// --------------------------- J: scatter ------------------------------------
__global__ __launch_bounds__(256) void k_scatter(const float* __restrict__ gout,
                                                 const int* __restrict__ segid,
                                                 const int* __restrict__ pref,
                                                 float* __restrict__ out) {
  int d = threadIdx.x;
  for (int rr = 0; rr < 32; ++rr) {
    int row = blockIdx.x * 32 + rr;
    int b = row >> 10;
    int l = segid[row];
    out[(size_t)row * 256 + d] = gout[((size_t)pref[b] + l) * 256 + d];
  }
}

// ---------------------------------------------------------------------------
extern "C" void kernel_launch(void* const* d_in, const int* in_sizes, int n_in,
                              void* d_out, int out_size, void* d_ws, size_t ws_size,
                              hipStream_t stream) {
  const float* x   = (const float*)d_in[0];
  const float* Wih = (const float*)d_in[1];
  const float* Whh = (const float*)d_in[2];
  const float* bih = (const float*)d_in[3];
  const float* bhh = (const float*)d_in[4];
  float* out = (float*)d_out;
  char* w = (char*)d_ws;

  const size_t o_cs1   = 0;
  const size_t o_cs2   = 67110912;
  const size_t o_diffs = 134221824;
  const size_t o_h1    = 134484224;
  const size_t o_h2    = 134746368;
  const size_t o_meta  = 135008512;
  const size_t o_keep  = 135008768;
  const size_t o_segid = 135074560;
  const size_t o_bnd   = 135336704;
  const size_t o_nseg  = 135599360;
  const size_t o_pref  = 135599616;
  const size_t o_gi    = 135600128;
  const size_t NEED    = 236460032;
  if (ws_size < NEED) return;

  float* cs1 = (float*)(w + o_cs1);
  float* cs2 = (float*)(w + o_cs2);
  float* diffs = (float*)(w + o_diffs);
  unsigned* h1 = (unsigned*)(w + o_h1);
  unsigned* h2 = (unsigned*)(w + o_h2);
  unsigned* meta = (unsigned*)(w + o_meta);
  unsigned char* keep = (unsigned char*)(w + o_keep);
  int* segid = (int*)(w + o_segid);
  int* bnd = (int*)(w + o_bnd);
  int* nseg = (int*)(w + o_nseg);
  int* pref = (int*)(w + o_pref);
  float* gi = (float*)(w + o_gi);
  float* carr = (float*)(w + o_gi);   // 524,288 B; dead before k_gi writes gi
  float* comp = cs1;                  // reuse (cs1 dead after k_diffs)
  float* gout = cs2;                  // reuse
  float* sink = (float*)(w + o_meta + 192);

  hipMemsetAsync(h1, 0, 262144, stream);
  hipMemsetAsync(h2, 0, 262144, stream);

  k_warm   <<<dim3(16384),  dim3(256),  0, stream>>>((const float4*)x, sink);
  k_carry  <<<dim3(8),      dim3(64),   0, stream>>>(x, carr);
  k_spread <<<dim3(512),    dim3(256),  0, stream>>>(x, carr, cs1, cs2);
  k_diffs  <<<dim3(1025),   dim3(64),   0, stream>>>(cs1, cs2, diffs);
  k_hist1  <<<dim3(257),    dim3(256),  0, stream>>>(diffs, h1);
  k_sel_hi <<<dim3(1),      dim3(256),  0, stream>>>(h1, meta);
  k_hist2  <<<dim3(257),    dim3(256),  0, stream>>>(diffs, meta, h2);
  k_sel_lo <<<dim3(1),      dim3(256),  0, stream>>>(h2, meta);
  k_keep   <<<dim3(1),      dim3(64),   0, stream>>>(diffs, meta, keep);
  k_segment<<<dim3(64),     dim3(1024), 0, stream>>>(keep, segid, bnd, nseg);
  k_prefix <<<dim3(1),      dim3(64),   0, stream>>>(nseg, pref);
  k_pool   <<<dim3(2048),   dim3(256),  0, stream>>>(x, bnd, nseg, pref, comp);
  k_gi     <<<dim3(513, 6), dim3(256),  0, stream>>>(comp, Wih, bih, bhh, pref, gi);
  k_gru    <<<dim3(64),     dim3(768),  0, stream>>>(gi, Whh, bhh, nseg, pref, gout);
  k_scatter<<<dim3(2048),   dim3(256),  0, stream>>>(gout, segid, pref, out);
}

// Round 6
// 1907.356 us; speedup vs baseline: 4.1491x; 1.1851x over previous
//
#include <hip/hip_runtime.h>
#include <cstdint>
#include <cstddef>
#include <cmath>

// ---------------------------------------------------------------------------
// Pipeline:
//   A0 k_warm   : pull x into L2/L3 (full-GPU streaming read, ~13us)
//   A1 k_carry  : exact sequential fl cumsum chains; per block: 1 chain wave
//                 consuming a 256-row LDS double-buffer + 3 stager waves
//                 (global_load_lds x16B). Writes 256-row checkpoints only.
//   A2 k_spread : 512 blocks replay each 256-row chunk from its exact carry
//                 (identical rounding sequence -> bit-exact), coalesced IO
//   B  k_diffs  : exact numpy-pairwise variance->diffs (float4 loads)
//   C  k_hist1/k_sel_hi/k_hist2/k_sel_lo : exact top-32768 radix select
//   D  k_keep   : keep flags, stable tie ranks
//   E  k_segment: per-batch boundary lists + frame->segment map
//   F  k_prefix : ragged row offsets
//   G  k_pool   : segment means (comp)
//   H  k_gi     : gi = comp @ W_ih^T + biases  [fp32 GEMM]
//   I  k_gru    : sequential GRU, 768 thr/block, k-half split W in VGPRs,
//                 uniform b128 h reads, raw-barrier sync, gi prefetch
//   J  k_scatter: out[b,t,:] = gru_out[b, seg(t), :]
// ---------------------------------------------------------------------------

#define NPOS 65537
#define KSEL 32768u

typedef _Float16 f16x2 __attribute__((ext_vector_type(2)));
typedef _Float16 f16x8 __attribute__((ext_vector_type(8)));

#if defined(__has_builtin)
#if __has_builtin(__builtin_amdgcn_fdot2)
#define HAVE_FDOT2 1
#endif
#endif

__device__ __forceinline__ float fdot2f(f16x2 a, f16x2 b, float c) {
#ifdef HAVE_FDOT2
  return __builtin_amdgcn_fdot2(a, b, c, false);
#else
  c += (float)a.x * (float)b.x;
  c += (float)a.y * (float)b.y;
  return c;
#endif
}

// --------------------------- A0: warm x into cache -------------------------
__global__ __launch_bounds__(256) void k_warm(const float4* __restrict__ x4,
                                              float* __restrict__ sink) {
  size_t i = (size_t)blockIdx.x * 256 + threadIdx.x;
  float4 v = x4[i];
  float s = (v.x + v.y) + (v.z + v.w);
  if (s == 1.23456789e-33f) sink[0] = s;  // deterministically false; keeps loads
}

// --------------------------- A1: carry chains ------------------------------
// 8 blocks x 256 threads (4 waves). Block b: SQ=b>>2 (plain vs squared),
// cols j0=(b&3)*64. Wave 0 = serial fl-chain (lane l owns col j0+l), reading
// rows from a 2x(256x64) LDS double-buffer; waves 1-3 stage chunk c+1 with
// global_load_lds x16B (4 rows per instr, per-lane global source) while the
// chain consumes chunk c. One barrier pair per 256-row chunk.
// Writes ONLY the 256-row checkpoints; k_spread replays each chunk.
__global__ __launch_bounds__(256) void k_carry(const float* __restrict__ x,
                                               float* __restrict__ carr) {
  __shared__ __align__(16) float lds[2 * 256 * 64];   // 128 KiB
  const int b = blockIdx.x;
  const int sq = b >> 2;
  const int j0 = (b & 3) * 64;
  const int wid = threadIdx.x >> 6;
  const int l = threadIdx.x & 63;

  if (wid != 0) {
    // ----- stagers -----
    const int wsel = wid - 1;   // 0..2; handles 4-row groups g with g%3==wsel
    const size_t lane_off = (size_t)(l >> 4) * 256 + (size_t)(l & 15) * 4;
    for (int c = 0; c <= 256; ++c) {
      if (c < 256) {
        const float* src = x + (size_t)c * 256 * 256 + j0 + lane_off;
        float* dbase = lds + (c & 1) * 16384;
        for (int g = wsel; g < 64; g += 3) {
          __builtin_amdgcn_global_load_lds(
              (const __attribute__((address_space(1))) void*)(src + (size_t)g * 1024),
              (__attribute__((address_space(3))) void*)(dbase + g * 256),
              16, 0, 0);
        }
      }
      asm volatile("s_waitcnt vmcnt(0)" ::: "memory");
      __builtin_amdgcn_sched_barrier(0);
      __builtin_amdgcn_s_barrier();
      __builtin_amdgcn_sched_barrier(0);
    }
  } else {
    // ----- chain wave -----
#pragma clang fp contract(off)
    __builtin_amdgcn_s_barrier();        // chunk 0 staged
    __builtin_amdgcn_sched_barrier(0);
    float acc = 0.f;
    float* cw = carr + ((size_t)sq * 256) * 256 + j0 + l;
    if (sq) {
      for (int c = 0; c < 256; ++c) {
        cw[(size_t)c * 256] = acc;       // carry BEFORE chunk c's rows
        const float* lp = lds + (c & 1) * 16384 + l;
#pragma unroll 16
        for (int r = 0; r < 256; ++r) {
          float v = lp[r * 64];
          v = v * v;                     // rounded square, then add (no FMA)
          acc = acc + v;
        }
        asm volatile("s_waitcnt lgkmcnt(0)" ::: "memory");
        __builtin_amdgcn_sched_barrier(0);
        __builtin_amdgcn_s_barrier();
        __builtin_amdgcn_sched_barrier(0);
      }
    } else {
      for (int c = 0; c < 256; ++c) {
        cw[(size_t)c * 256] = acc;
        const float* lp = lds + (c & 1) * 16384 + l;
#pragma unroll 16
        for (int r = 0; r < 256; ++r) {
          float v = lp[r * 64];
          acc = acc + v;
        }
        asm volatile("s_waitcnt lgkmcnt(0)" ::: "memory");
        __builtin_amdgcn_sched_barrier(0);
        __builtin_amdgcn_s_barrier();
        __builtin_amdgcn_sched_barrier(0);
      }
    }
  }
}

// --------------------------- A2: spread chunks -----------------------------
// 512 blocks x 256 threads: block = (sq, chunk). Replays the 256-row chain
// of its chunk starting from the exact carry -> bit-identical fl sequence.
// Coalesced 1KB row loads/stores; D=4 x U=8 register pipeline.
__global__ __launch_bounds__(256) void k_spread(const float* __restrict__ x,
                                                const float* __restrict__ carr,
                                                float* __restrict__ cs1,
                                                float* __restrict__ cs2) {
#pragma clang fp contract(off)
  const int blk = blockIdx.x;
  const int sq = blk >> 8;
  const int ch = blk & 255;
  const int col = threadIdx.x;
  float* dst = sq ? cs2 : cs1;
  float c = carr[((size_t)sq * 256 + ch) * 256 + col];
  const float* gp = x + (size_t)ch * 256 * 256 + col;
  float* sp = dst + ((size_t)ch * 256 + 1) * 256 + col;
  if (ch == 0) dst[col] = 0.f;        // p=0 row (enc zero prepend)
  float buf[4][8];
#pragma unroll
  for (int d = 0; d < 3; ++d)
#pragma unroll
    for (int u = 0; u < 8; ++u)
      buf[d][u] = gp[(size_t)(d * 8 + u) * 256];
  for (int g = 0; g < 8; ++g) {
#pragma unroll
    for (int d = 0; d < 4; ++d) {
      const int s = g * 4 + d;        // 8-row group (0..31)
      if (s + 3 < 32) {
        const float* ld = gp + (size_t)(s + 3) * 8 * 256;
#pragma unroll
        for (int u = 0; u < 8; ++u)
          buf[(d + 3) & 3][u] = ld[(size_t)u * 256];
      }
#pragma unroll
      for (int u = 0; u < 8; ++u) {
        float v = buf[d][u];
        if (sq) v = v * v;
        c = c + v;
        sp[(size_t)(s * 8 + u) * 256] = c;
      }
    }
  }
}

// --------------------------- B: exact diffs --------------------------------
// Same op order as numpy: s1/2, s2/2, pairwise mean (two 128-blocks,
// 8 accumulators, specific combine), sqrt via double. float4 loads.
__device__ __forceinline__ float dterm(float ap, float am, float bp, float bm) {
#pragma clang fp contract(off)
  float s1 = ap - am;
  float s2 = bp - bm;
  float t1 = s1 * 0.5f;
  float u = s2 * 0.5f;
  return u - t1 * t1;
}

__global__ __launch_bounds__(64) void k_diffs(const float* __restrict__ cs1,
                                              const float* __restrict__ cs2,
                                              float* __restrict__ diffs) {
#pragma clang fp contract(off)
  int p = blockIdx.x * 64 + threadIdx.x;
  if (p >= NPOS) return;
  if (p == 0 || p == NPOS - 1) { diffs[p] = 1e10f; return; }
  const float4* am4 = (const float4*)(cs1 + (size_t)(p - 1) * 256);
  const float4* ap4 = (const float4*)(cs1 + (size_t)(p + 1) * 256);
  const float4* bm4 = (const float4*)(cs2 + (size_t)(p - 1) * 256);
  const float4* bp4 = (const float4*)(cs2 + (size_t)(p + 1) * 256);
  float blk[2];
  for (int half = 0; half < 2; ++half) {
    float r[8];
    for (int i = 0; i < 16; ++i) {
      int q = half * 32 + i * 2;
      float4 a0 = ap4[q], m0 = am4[q], b0 = bp4[q], n0 = bm4[q];
      float4 a1 = ap4[q + 1], m1 = am4[q + 1], b1 = bp4[q + 1], n1 = bm4[q + 1];
      float e0 = dterm(a0.x, m0.x, b0.x, n0.x);
      float e1 = dterm(a0.y, m0.y, b0.y, n0.y);
      float e2 = dterm(a0.z, m0.z, b0.z, n0.z);
      float e3 = dterm(a0.w, m0.w, b0.w, n0.w);
      float e4 = dterm(a1.x, m1.x, b1.x, n1.x);
      float e5 = dterm(a1.y, m1.y, b1.y, n1.y);
      float e6 = dterm(a1.z, m1.z, b1.z, n1.z);
      float e7 = dterm(a1.w, m1.w, b1.w, n1.w);
      if (i == 0) {
        r[0] = e0; r[1] = e1; r[2] = e2; r[3] = e3;
        r[4] = e4; r[5] = e5; r[6] = e6; r[7] = e7;
      } else {
        r[0] += e0; r[1] += e1; r[2] += e2; r[3] += e3;
        r[4] += e4; r[5] += e5; r[6] += e6; r[7] += e7;
      }
    }
    blk[half] = ((r[0] + r[1]) + (r[2] + r[3])) + ((r[4] + r[5]) + (r[6] + r[7]));
  }
  float mean = (blk[0] + blk[1]) / 256.0f;
  float mx = mean > 0.0f ? mean : 0.0f;
  diffs[p] = (float)::sqrt((double)mx);
}

// --------------------------- C: radix select -------------------------------
__global__ void k_hist1(const float* __restrict__ diffs, unsigned* __restrict__ h1) {
  int p = blockIdx.x * 256 + threadIdx.x;
  if (p >= NPOS) return;
  unsigned key = __float_as_uint(diffs[p]);
  atomicAdd(&h1[key >> 16], 1u);
}

__global__ void k_sel_hi(const unsigned* __restrict__ h1, unsigned* __restrict__ meta) {
  __shared__ unsigned loc[256];
  int t = threadIdx.x;
  unsigned s = 0;
  for (int i = 0; i < 256; ++i) s += h1[t * 256 + i];
  loc[t] = s;
  __syncthreads();
  if (t == 0) {
    unsigned run = 0; int tt = 255;
    for (; tt > 0; --tt) { if (run + loc[tt] >= KSEL) break; run += loc[tt]; }
    unsigned r2 = run;
    for (int i = 255; i >= 0; --i) {
      unsigned c = h1[tt * 256 + i];
      if (r2 + c >= KSEL) { meta[0] = (unsigned)(tt * 256 + i); meta[1] = r2; break; }
      r2 += c;
    }
  }
}

__global__ void k_hist2(const float* __restrict__ diffs, const unsigned* __restrict__ meta,
                        unsigned* __restrict__ h2) {
  int p = blockIdx.x * 256 + threadIdx.x;
  if (p >= NPOS) return;
  unsigned key = __float_as_uint(diffs[p]);
  if ((key >> 16) == meta[0]) atomicAdd(&h2[key & 0xffffu], 1u);
}

__global__ void k_sel_lo(const unsigned* __restrict__ h2, unsigned* __restrict__ meta) {
  __shared__ unsigned loc[256];
  int t = threadIdx.x;
  unsigned s = 0;
  for (int i = 0; i < 256; ++i) s += h2[t * 256 + i];
  loc[t] = s;
  __syncthreads();
  if (t == 0) {
    unsigned remaining = KSEL - meta[1];
    unsigned run = 0; int tt = 255;
    for (; tt > 0; --tt) { if (run + loc[tt] >= remaining) break; run += loc[tt]; }
    unsigned r2 = run;
    for (int i = 255; i >= 0; --i) {
      unsigned c = h2[tt * 256 + i];
      if (r2 + c >= remaining) {
        meta[2] = (meta[0] << 16) | (unsigned)(tt * 256 + i);
        meta[3] = remaining - r2;
        break;
      }
      r2 += c;
    }
  }
}

// --------------------------- D: keep flags ---------------------------------
__global__ __launch_bounds__(64) void k_keep(const float* __restrict__ diffs,
                                             const unsigned* __restrict__ meta,
                                             unsigned char* __restrict__ keep) {
  int lane = threadIdx.x;
  unsigned Kstar = meta[2], need = meta[3];
  unsigned base = 0;
  float v[4], nv[4];
#pragma unroll
  for (int q = 0; q < 4; ++q) nv[q] = diffs[q * 64 + lane];
  for (int it = 0; it < 257; ++it) {
#pragma unroll
    for (int q = 0; q < 4; ++q) v[q] = nv[q];
    if (it < 256) {
      int nb = (it + 1) * 256;
#pragma unroll
      for (int q = 0; q < 4; ++q) {
        int idx = nb + q * 64 + lane;
        nv[q] = (idx < NPOS) ? diffs[idx] : 0.f;
      }
    }
#pragma unroll
    for (int q = 0; q < 4; ++q) {
      int p = it * 256 + q * 64 + lane;
      bool valid = p < NPOS;
      unsigned key = valid ? __float_as_uint(v[q]) : 0u;
      bool eq = valid && (key == Kstar);
      unsigned long long m = __ballot(eq);
      unsigned rank = base + (unsigned)__popcll(m & ((1ull << lane) - 1ull));
      bool k = valid && ((key > Kstar) || (eq && rank < need) || ((p & 1023) == 0));
      if (valid) keep[p] = (unsigned char)k;
      base += (unsigned)__popcll(m);
    }
  }
}

// --------------------------- E: per-batch segments -------------------------
__global__ __launch_bounds__(1024) void k_segment(const unsigned char* __restrict__ keep,
                                                  int* __restrict__ segid,
                                                  int* __restrict__ bnd,
                                                  int* __restrict__ nseg) {
  __shared__ int s[1024];
  int b = blockIdx.x, t = threadIdx.x;
  int f = (t >= 1) ? (int)keep[b * 1024 + t] : 0;
  s[t] = f;
  __syncthreads();
  for (int off = 1; off < 1024; off <<= 1) {
    int v = s[t];
    int add = (t >= off) ? s[t - off] : 0;
    __syncthreads();
    s[t] = v + add;
    __syncthreads();
  }
  int sc = s[t];
  segid[b * 1024 + t] = sc;
  if (f) bnd[b * 1026 + sc] = t;
  if (t == 0) bnd[b * 1026] = 0;
  if (t == 1023) {
    int m = sc + 1;
    nseg[b] = m;
    bnd[b * 1026 + m] = 1024;
  }
}

__global__ __launch_bounds__(64) void k_prefix(const int* __restrict__ nseg,
                                               int* __restrict__ pref) {
  int lane = threadIdx.x;
  int s = nseg[lane];
  for (int off = 1; off < 64; off <<= 1) {
    int u = __shfl_up(s, off);
    if (lane >= off) s += u;
  }
  pref[lane + 1] = s;
  if (lane == 0) pref[0] = 0;
}

// --------------------------- G: segment means ------------------------------
__global__ __launch_bounds__(256) void k_pool(const float* __restrict__ x,
                                              const int* __restrict__ bnd,
                                              const int* __restrict__ nseg,
                                              const int* __restrict__ pref,
                                              float* __restrict__ comp) {
  int d = threadIdx.x;
  for (int s = 0; s < 32; ++s) {
    int sid = blockIdx.x * 32 + s;
    int b = sid >> 10, li = sid & 1023;
    if (li >= nseg[b]) continue;
    int s0 = bnd[b * 1026 + li], e0 = bnd[b * 1026 + li + 1];
    float acc = 0.f;
    for (int t = s0; t < e0; ++t) acc += x[((size_t)b * 1024 + t) * 256 + d];
    comp[((size_t)pref[b] + li) * 256 + d] = acc / (float)(e0 - s0);
  }
}

// --------------------------- H: gi GEMM (fp32) -----------------------------
__global__ __launch_bounds__(256) void k_gi(const float* __restrict__ comp,
                                            const float* __restrict__ Wih,
                                            const float* __restrict__ bih,
                                            const float* __restrict__ bhh,
                                            const int* __restrict__ pref,
                                            float* __restrict__ gi) {
  int total = pref[64];
  int r0 = blockIdx.x * 64;
  if (r0 >= total) return;
  int c0 = blockIdx.y * 128;
  __shared__ float As[64][64];
  __shared__ float Bs[64 * 132];
  int tid = threadIdx.x;
  int rg = tid >> 5, cl = tid & 31;
  float acc[8][4];
#pragma unroll
  for (int i = 0; i < 8; ++i)
#pragma unroll
    for (int q = 0; q < 4; ++q) acc[i][q] = 0.f;

  for (int k0 = 0; k0 < 256; k0 += 64) {
#pragma unroll
    for (int i = 0; i < 4; ++i) {
      int idx = tid + i * 256;
      int row = idx >> 4, kq = idx & 15;
      int rr = r0 + row;
      float4 v;
      if (rr < total) v = *reinterpret_cast<const float4*>(comp + (size_t)rr * 256 + k0 + kq * 4);
      else { v.x = 0.f; v.y = 0.f; v.z = 0.f; v.w = 0.f; }
      *reinterpret_cast<float4*>(&As[row][kq * 4]) = v;
    }
#pragma unroll
    for (int i = 0; i < 8; ++i) {
      int idx = tid + i * 256;
      int row = idx >> 4, kq = idx & 15;
      float4 v = *reinterpret_cast<const float4*>(Wih + (size_t)(c0 + row) * 256 + k0 + kq * 4);
      Bs[(kq * 4 + 0) * 132 + row] = v.x;
      Bs[(kq * 4 + 1) * 132 + row] = v.y;
      Bs[(kq * 4 + 2) * 132 + row] = v.z;
      Bs[(kq * 4 + 3) * 132 + row] = v.w;
    }
    __syncthreads();
#pragma unroll 4
    for (int k = 0; k < 64; ++k) {
      float a[8], bv[4];
#pragma unroll
      for (int i = 0; i < 8; ++i) a[i] = As[rg * 8 + i][k];
#pragma unroll
      for (int q = 0; q < 4; ++q) bv[q] = Bs[k * 132 + cl + 32 * q];
#pragma unroll
      for (int i = 0; i < 8; ++i)
#pragma unroll
        for (int q = 0; q < 4; ++q) acc[i][q] += a[i] * bv[q];
    }
    __syncthreads();
  }
#pragma unroll
  for (int q = 0; q < 4; ++q) {
    int c = c0 + cl + 32 * q;
    float bias = bih[c] + (c < 512 ? bhh[c] : 0.f);
#pragma unroll
    for (int i = 0; i < 8; ++i) {
      int rr = r0 + rg * 8 + i;
      if (rr < total) gi[(size_t)rr * 768 + c] = acc[i][q] + bias;
    }
  }
}

// --------------------------- I: GRU ----------------------------------------
// 64 blocks x 768 threads (12 waves, 3/SIMD). Thread (pr, half) owns rows
// {pr, 384+pr} restricted to k-half `half` (2 x 64 f16x2 = 128 VGPRs).
// h (f16) read as wave-uniform ds_read_b128 (16/wave/step). Partials
// combined via LDS float2. Raw s_barrier sync (no vmcnt drain) so gout
// stores + next-step gi prefetch stay in flight.
__global__ __launch_bounds__(768, 3) void k_gru(const float* __restrict__ gi,
                                                const float* __restrict__ Whh,
                                                const float* __restrict__ bhh,
                                                const int* __restrict__ nseg,
                                                const int* __restrict__ pref,
                                                float* __restrict__ gout) {
  const int b = blockIdx.x;
  const int t = threadIdx.x;
  const int m = nseg[b];
  const size_t base = (size_t)pref[b];
  const int half = (t >= 384) ? 1 : 0;     // wave-uniform (waves 0-5 / 6-11)
  const int pr = t - half * 384;           // 0..383
  const int row0 = pr, row1 = 384 + pr;
  const int k0 = half * 128;

  f16x2 w0[64], w1[64];
#pragma unroll
  for (int i = 0; i < 32; ++i) {
    float4 v = *(const float4*)(Whh + (size_t)row0 * 256 + k0 + i * 4);
    f16x2 aa; aa.x = (_Float16)v.x; aa.y = (_Float16)v.y; w0[2 * i] = aa;
    f16x2 ab; ab.x = (_Float16)v.z; ab.y = (_Float16)v.w; w0[2 * i + 1] = ab;
    float4 u = *(const float4*)(Whh + (size_t)row1 * 256 + k0 + i * 4);
    f16x2 ba; ba.x = (_Float16)u.x; ba.y = (_Float16)u.y; w1[2 * i] = ba;
    f16x2 bb; bb.x = (_Float16)u.z; bb.y = (_Float16)u.w; w1[2 * i + 1] = bb;
  }

  __shared__ f16x8 hbuf8[32];     // h as f16 (256 vals); [half*16+i] uniform
  __shared__ float2 pp2[768];     // per-row {half0, half1} partials

  float bn = (t < 256) ? bhh[512 + t] : 0.f;
  float hreg = 0.f;               // finish thread t<256 owns h[t] in f32
  if (t < 64) {
    f16x8 z = (f16x8)(_Float16)0.f;
    if (t < 32) hbuf8[t] = z;
  }
  __syncthreads();

  float cr = 0.f, cz = 0.f, cn = 0.f;
  if (t < 256) {
    const float* g0 = gi + base * 768;
    cr = g0[t]; cz = g0[256 + t]; cn = g0[512 + t];
  }

  for (int l = 0; l < m; ++l) {
    float nr = 0.f, nz = 0.f, nn = 0.f;
    if (t < 256 && l + 1 < m) {            // prefetch next step's gi
      const float* g1 = gi + (base + l + 1) * 768;
      nr = g1[t]; nz = g1[256 + t]; nn = g1[512 + t];
    }
    float a0 = 0.f, a1 = 0.f, a2 = 0.f, a3 = 0.f;
#pragma unroll
    for (int i = 0; i < 16; ++i) {
      f16x8 hv = hbuf8[half * 16 + i];     // uniform ds_read_b128
      f16x2 p0; p0.x = hv[0]; p0.y = hv[1];
      f16x2 p1; p1.x = hv[2]; p1.y = hv[3];
      f16x2 p2; p2.x = hv[4]; p2.y = hv[5];
      f16x2 p3; p3.x = hv[6]; p3.y = hv[7];
      a0 = fdot2f(w0[4 * i + 0], p0, a0);
      a2 = fdot2f(w0[4 * i + 1], p1, a2);
      a0 = fdot2f(w0[4 * i + 2], p2, a0);
      a2 = fdot2f(w0[4 * i + 3], p3, a2);
      a1 = fdot2f(w1[4 * i + 0], p0, a1);
      a3 = fdot2f(w1[4 * i + 1], p1, a3);
      a1 = fdot2f(w1[4 * i + 2], p2, a1);
      a3 = fdot2f(w1[4 * i + 3], p3, a3);
    }
    float* ppf = (float*)pp2;
    ppf[row0 * 2 + half] = a0 + a2;
    ppf[row1 * 2 + half] = a1 + a3;
    asm volatile("s_waitcnt lgkmcnt(0)" ::: "memory");
    __builtin_amdgcn_sched_barrier(0);
    __builtin_amdgcn_s_barrier();
    __builtin_amdgcn_sched_barrier(0);
    if (t < 256) {
      float2 qr = pp2[t];
      float2 qz = pp2[256 + t];
      float2 qn = pp2[512 + t];
      float sr = qr.x + qr.y;
      float sz = qz.x + qz.y;
      float sn = qn.x + qn.y + bn;
      float r = 1.f / (1.f + __expf(-(cr + sr)));
      float z = 1.f / (1.f + __expf(-(cz + sz)));
      float arg = cn + r * sn;
      float n = 2.f / (1.f + __expf(-2.f * arg)) - 1.f;   // tanh
      float hnew = (1.f - z) * n + z * hreg;
      hreg = hnew;
      ((_Float16*)hbuf8)[t] = (_Float16)hnew;
      gout[(base + l) * 256 + t] = hnew;
    }
    cr = nr; cz = nz; cn = nn;
    asm volatile("s_waitcnt lgkmcnt(0)" ::: "memory");
    __builtin_amdgcn_sched_barrier(0);
    __builtin_amdgcn_s_barrier();
    __builtin_amdgcn_sched_barrier(0);
  }
}

// --------------------------- J: scatter ------------------------------------
__global__ __launch_bounds__(256) void k_scatter(const float* __restrict__ gout,
                                                 const int* __restrict__ segid,
                                                 const int* __restrict__ pref,
                                                 float* __restrict__ out) {
  int d = threadIdx.x;
  for (int rr = 0; rr < 32; ++rr) {
    int row = blockIdx.x * 32 + rr;
    int b = row >> 10;
    int l = segid[row];
    out[(size_t)row * 256 + d] = gout[((size_t)pref[b] + l) * 256 + d];
  }
}

// ---------------------------------------------------------------------------
extern "C" void kernel_launch(void* const* d_in, const int* in_sizes, int n_in,
                              void* d_out, int out_size, void* d_ws, size_t ws_size,
                              hipStream_t stream) {
  const float* x   = (const float*)d_in[0];
  const float* Wih = (const float*)d_in[1];
  const float* Whh = (const float*)d_in[2];
  const float* bih = (const float*)d_in[3];
  const float* bhh = (const float*)d_in[4];
  float* out = (float*)d_out;
  char* w = (char*)d_ws;

  const size_t o_cs1   = 0;
  const size_t o_cs2   = 67110912;
  const size_t o_diffs = 134221824;
  const size_t o_h1    = 134484224;
  const size_t o_h2    = 134746368;
  const size_t o_meta  = 135008512;
  const size_t o_keep  = 135008768;
  const size_t o_segid = 135074560;
  const size_t o_bnd   = 135336704;
  const size_t o_nseg  = 135599360;
  const size_t o_pref  = 135599616;
  const size_t o_gi    = 135600128;
  const size_t NEED    = 236460032;
  if (ws_size < NEED) return;

  float* cs1 = (float*)(w + o_cs1);
  float* cs2 = (float*)(w + o_cs2);
  float* diffs = (float*)(w + o_diffs);
  unsigned* h1 = (unsigned*)(w + o_h1);
  unsigned* h2 = (unsigned*)(w + o_h2);
  unsigned* meta = (unsigned*)(w + o_meta);
  unsigned char* keep = (unsigned char*)(w + o_keep);
  int* segid = (int*)(w + o_segid);
  int* bnd = (int*)(w + o_bnd);
  int* nseg = (int*)(w + o_nseg);
  int* pref = (int*)(w + o_pref);
  float* gi = (float*)(w + o_gi);
  float* carr = (float*)(w + o_gi);   // 524,288 B; dead before k_gi writes gi
  float* comp = cs1;                  // reuse (cs1 dead after k_diffs)
  float* gout = cs2;                  // reuse
  float* sink = (float*)(w + o_meta + 192);

  hipMemsetAsync(h1, 0, 262144, stream);
  hipMemsetAsync(h2, 0, 262144, stream);

  k_warm   <<<dim3(16384),  dim3(256),  0, stream>>>((const float4*)x, sink);
  k_carry  <<<dim3(8),      dim3(256),  0, stream>>>(x, carr);
  k_spread <<<dim3(512),    dim3(256),  0, stream>>>(x, carr, cs1, cs2);
  k_diffs  <<<dim3(1025),   dim3(64),   0, stream>>>(cs1, cs2, diffs);
  k_hist1  <<<dim3(257),    dim3(256),  0, stream>>>(diffs, h1);
  k_sel_hi <<<dim3(1),      dim3(256),  0, stream>>>(h1, meta);
  k_hist2  <<<dim3(257),    dim3(256),  0, stream>>>(diffs, meta, h2);
  k_sel_lo <<<dim3(1),      dim3(256),  0, stream>>>(h2, meta);
  k_keep   <<<dim3(1),      dim3(64),   0, stream>>>(diffs, meta, keep);
  k_segment<<<dim3(64),     dim3(1024), 0, stream>>>(keep, segid, bnd, nseg);
  k_prefix <<<dim3(1),      dim3(64),   0, stream>>>(nseg, pref);
  k_pool   <<<dim3(2048),   dim3(256),  0, stream>>>(x, bnd, nseg, pref, comp);
  k_gi     <<<dim3(513, 6), dim3(256),  0, stream>>>(comp, Wih, bih, bhh, pref, gi);
  k_gru    <<<dim3(64),     dim3(768),  0, stream>>>(gi, Whh, bhh, nseg, pref, gout);
  k_scatter<<<dim3(2048),   dim3(256),  0, stream>>>(gout, segid, pref, out);
}

// Round 7
// 1904.315 us; speedup vs baseline: 4.1557x; 1.0016x over previous
//
#include <hip/hip_runtime.h>
#include <cstdint>
#include <cstddef>
#include <cmath>

// ---------------------------------------------------------------------------
// Pipeline:
//   A0 k_warm   : pull x into L2/L3 (full-GPU streaming read, ~13us)
//   A1 k_carry  : exact sequential fl cumsum chains; per block: 1 chain wave
//                 consuming a 256-row LDS double-buffer + 3 stager waves
//                 (global_load_lds x16B). Writes 256-row checkpoints only.
//   A2 k_spread : 512 blocks replay each 256-row chunk from its exact carry
//                 (identical rounding sequence -> bit-exact), coalesced IO
//   B  k_diffs  : exact numpy-pairwise variance->diffs (float4 loads)
//   C  k_hist1/k_sel_hi/k_hist2/k_sel_lo : exact top-32768 radix select
//   D  k_keep   : keep flags, stable tie ranks
//   E  k_segment: per-batch boundary lists + frame->segment map
//   F  k_prefix : ragged row offsets
//   G  k_pool   : segment means (comp)
//   H  k_gi     : gi = comp @ W_ih^T + biases  [fp32 GEMM]
//   I  k_gru    : sequential GRU, 512 thr/block (VGPR cap 256), thread owns
//                 3 gate rows x k-half in 192 f16x2 VGPRs, uniform b128 h
//                 reads, raw-barrier sync, gi prefetch
//   J  k_scatter: out[b,t,:] = gru_out[b, seg(t), :]
// ---------------------------------------------------------------------------

#define NPOS 65537
#define KSEL 32768u

typedef _Float16 f16x2 __attribute__((ext_vector_type(2)));
typedef _Float16 f16x8 __attribute__((ext_vector_type(8)));

#if defined(__has_builtin)
#if __has_builtin(__builtin_amdgcn_fdot2)
#define HAVE_FDOT2 1
#endif
#endif

__device__ __forceinline__ float fdot2f(f16x2 a, f16x2 b, float c) {
#ifdef HAVE_FDOT2
  return __builtin_amdgcn_fdot2(a, b, c, false);
#else
  c += (float)a.x * (float)b.x;
  c += (float)a.y * (float)b.y;
  return c;
#endif
}

// --------------------------- A0: warm x into cache -------------------------
__global__ __launch_bounds__(256) void k_warm(const float4* __restrict__ x4,
                                              float* __restrict__ sink) {
  size_t i = (size_t)blockIdx.x * 256 + threadIdx.x;
  float4 v = x4[i];
  float s = (v.x + v.y) + (v.z + v.w);
  if (s == 1.23456789e-33f) sink[0] = s;  // deterministically false; keeps loads
}

// --------------------------- A1: carry chains ------------------------------
// 8 blocks x 256 threads (4 waves). Block b: SQ=b>>2 (plain vs squared),
// cols j0=(b&3)*64. Wave 0 = serial fl-chain (lane l owns col j0+l), reading
// rows from a 2x(256x64) LDS double-buffer; waves 1-3 stage chunk c+1 with
// global_load_lds x16B while the chain consumes chunk c. One barrier pair
// per 256-row chunk. Writes ONLY the 256-row checkpoints.
__global__ __launch_bounds__(256) void k_carry(const float* __restrict__ x,
                                               float* __restrict__ carr) {
  __shared__ __align__(16) float lds[2 * 256 * 64];   // 128 KiB
  const int b = blockIdx.x;
  const int sq = b >> 2;
  const int j0 = (b & 3) * 64;
  const int wid = threadIdx.x >> 6;
  const int l = threadIdx.x & 63;

  if (wid != 0) {
    // ----- stagers -----
    const int wsel = wid - 1;   // 0..2; handles 4-row groups g with g%3==wsel
    const size_t lane_off = (size_t)(l >> 4) * 256 + (size_t)(l & 15) * 4;
    for (int c = 0; c <= 256; ++c) {
      if (c < 256) {
        const float* src = x + (size_t)c * 256 * 256 + j0 + lane_off;
        float* dbase = lds + (c & 1) * 16384;
        for (int g = wsel; g < 64; g += 3) {
          __builtin_amdgcn_global_load_lds(
              (const __attribute__((address_space(1))) void*)(src + (size_t)g * 1024),
              (__attribute__((address_space(3))) void*)(dbase + g * 256),
              16, 0, 0);
        }
      }
      asm volatile("s_waitcnt vmcnt(0)" ::: "memory");
      __builtin_amdgcn_sched_barrier(0);
      __builtin_amdgcn_s_barrier();
      __builtin_amdgcn_sched_barrier(0);
    }
  } else {
    // ----- chain wave -----
#pragma clang fp contract(off)
    __builtin_amdgcn_s_barrier();        // chunk 0 staged
    __builtin_amdgcn_sched_barrier(0);
    float acc = 0.f;
    float* cw = carr + ((size_t)sq * 256) * 256 + j0 + l;
    if (sq) {
      for (int c = 0; c < 256; ++c) {
        cw[(size_t)c * 256] = acc;       // carry BEFORE chunk c's rows
        const float* lp = lds + (c & 1) * 16384 + l;
#pragma unroll 16
        for (int r = 0; r < 256; ++r) {
          float v = lp[r * 64];
          v = v * v;                     // rounded square, then add (no FMA)
          acc = acc + v;
        }
        asm volatile("s_waitcnt lgkmcnt(0)" ::: "memory");
        __builtin_amdgcn_sched_barrier(0);
        __builtin_amdgcn_s_barrier();
        __builtin_amdgcn_sched_barrier(0);
      }
    } else {
      for (int c = 0; c < 256; ++c) {
        cw[(size_t)c * 256] = acc;
        const float* lp = lds + (c & 1) * 16384 + l;
#pragma unroll 16
        for (int r = 0; r < 256; ++r) {
          float v = lp[r * 64];
          acc = acc + v;
        }
        asm volatile("s_waitcnt lgkmcnt(0)" ::: "memory");
        __builtin_amdgcn_sched_barrier(0);
        __builtin_amdgcn_s_barrier();
        __builtin_amdgcn_sched_barrier(0);
      }
    }
  }
}

// --------------------------- A2: spread chunks -----------------------------
__global__ __launch_bounds__(256) void k_spread(const float* __restrict__ x,
                                                const float* __restrict__ carr,
                                                float* __restrict__ cs1,
                                                float* __restrict__ cs2) {
#pragma clang fp contract(off)
  const int blk = blockIdx.x;
  const int sq = blk >> 8;
  const int ch = blk & 255;
  const int col = threadIdx.x;
  float* dst = sq ? cs2 : cs1;
  float c = carr[((size_t)sq * 256 + ch) * 256 + col];
  const float* gp = x + (size_t)ch * 256 * 256 + col;
  float* sp = dst + ((size_t)ch * 256 + 1) * 256 + col;
  if (ch == 0) dst[col] = 0.f;        // p=0 row (enc zero prepend)
  float buf[4][8];
#pragma unroll
  for (int d = 0; d < 3; ++d)
#pragma unroll
    for (int u = 0; u < 8; ++u)
      buf[d][u] = gp[(size_t)(d * 8 + u) * 256];
  for (int g = 0; g < 8; ++g) {
#pragma unroll
    for (int d = 0; d < 4; ++d) {
      const int s = g * 4 + d;        // 8-row group (0..31)
      if (s + 3 < 32) {
        const float* ld = gp + (size_t)(s + 3) * 8 * 256;
#pragma unroll
        for (int u = 0; u < 8; ++u)
          buf[(d + 3) & 3][u] = ld[(size_t)u * 256];
      }
#pragma unroll
      for (int u = 0; u < 8; ++u) {
        float v = buf[d][u];
        if (sq) v = v * v;
        c = c + v;
        sp[(size_t)(s * 8 + u) * 256] = c;
      }
    }
  }
}

// --------------------------- B: exact diffs --------------------------------
__device__ __forceinline__ float dterm(float ap, float am, float bp, float bm) {
#pragma clang fp contract(off)
  float s1 = ap - am;
  float s2 = bp - bm;
  float t1 = s1 * 0.5f;
  float u = s2 * 0.5f;
  return u - t1 * t1;
}

__global__ __launch_bounds__(64) void k_diffs(const float* __restrict__ cs1,
                                              const float* __restrict__ cs2,
                                              float* __restrict__ diffs) {
#pragma clang fp contract(off)
  int p = blockIdx.x * 64 + threadIdx.x;
  if (p >= NPOS) return;
  if (p == 0 || p == NPOS - 1) { diffs[p] = 1e10f; return; }
  const float4* am4 = (const float4*)(cs1 + (size_t)(p - 1) * 256);
  const float4* ap4 = (const float4*)(cs1 + (size_t)(p + 1) * 256);
  const float4* bm4 = (const float4*)(cs2 + (size_t)(p - 1) * 256);
  const float4* bp4 = (const float4*)(cs2 + (size_t)(p + 1) * 256);
  float blk[2];
  for (int half = 0; half < 2; ++half) {
    float r[8];
    for (int i = 0; i < 16; ++i) {
      int q = half * 32 + i * 2;
      float4 a0 = ap4[q], m0 = am4[q], b0 = bp4[q], n0 = bm4[q];
      float4 a1 = ap4[q + 1], m1 = am4[q + 1], b1 = bp4[q + 1], n1 = bm4[q + 1];
      float e0 = dterm(a0.x, m0.x, b0.x, n0.x);
      float e1 = dterm(a0.y, m0.y, b0.y, n0.y);
      float e2 = dterm(a0.z, m0.z, b0.z, n0.z);
      float e3 = dterm(a0.w, m0.w, b0.w, n0.w);
      float e4 = dterm(a1.x, m1.x, b1.x, n1.x);
      float e5 = dterm(a1.y, m1.y, b1.y, n1.y);
      float e6 = dterm(a1.z, m1.z, b1.z, n1.z);
      float e7 = dterm(a1.w, m1.w, b1.w, n1.w);
      if (i == 0) {
        r[0] = e0; r[1] = e1; r[2] = e2; r[3] = e3;
        r[4] = e4; r[5] = e5; r[6] = e6; r[7] = e7;
      } else {
        r[0] += e0; r[1] += e1; r[2] += e2; r[3] += e3;
        r[4] += e4; r[5] += e5; r[6] += e6; r[7] += e7;
      }
    }
    blk[half] = ((r[0] + r[1]) + (r[2] + r[3])) + ((r[4] + r[5]) + (r[6] + r[7]));
  }
  float mean = (blk[0] + blk[1]) / 256.0f;
  float mx = mean > 0.0f ? mean : 0.0f;
  diffs[p] = (float)::sqrt((double)mx);
}

// --------------------------- C: radix select -------------------------------
__global__ void k_hist1(const float* __restrict__ diffs, unsigned* __restrict__ h1) {
  int p = blockIdx.x * 256 + threadIdx.x;
  if (p >= NPOS) return;
  unsigned key = __float_as_uint(diffs[p]);
  atomicAdd(&h1[key >> 16], 1u);
}

__global__ void k_sel_hi(const unsigned* __restrict__ h1, unsigned* __restrict__ meta) {
  __shared__ unsigned loc[256];
  int t = threadIdx.x;
  unsigned s = 0;
  for (int i = 0; i < 256; ++i) s += h1[t * 256 + i];
  loc[t] = s;
  __syncthreads();
  if (t == 0) {
    unsigned run = 0; int tt = 255;
    for (; tt > 0; --tt) { if (run + loc[tt] >= KSEL) break; run += loc[tt]; }
    unsigned r2 = run;
    for (int i = 255; i >= 0; --i) {
      unsigned c = h1[tt * 256 + i];
      if (r2 + c >= KSEL) { meta[0] = (unsigned)(tt * 256 + i); meta[1] = r2; break; }
      r2 += c;
    }
  }
}

__global__ void k_hist2(const float* __restrict__ diffs, const unsigned* __restrict__ meta,
                        unsigned* __restrict__ h2) {
  int p = blockIdx.x * 256 + threadIdx.x;
  if (p >= NPOS) return;
  unsigned key = __float_as_uint(diffs[p]);
  if ((key >> 16) == meta[0]) atomicAdd(&h2[key & 0xffffu], 1u);
}

__global__ void k_sel_lo(const unsigned* __restrict__ h2, unsigned* __restrict__ meta) {
  __shared__ unsigned loc[256];
  int t = threadIdx.x;
  unsigned s = 0;
  for (int i = 0; i < 256; ++i) s += h2[t * 256 + i];
  loc[t] = s;
  __syncthreads();
  if (t == 0) {
    unsigned remaining = KSEL - meta[1];
    unsigned run = 0; int tt = 255;
    for (; tt > 0; --tt) { if (run + loc[tt] >= remaining) break; run += loc[tt]; }
    unsigned r2 = run;
    for (int i = 255; i >= 0; --i) {
      unsigned c = h2[tt * 256 + i];
      if (r2 + c >= remaining) {
        meta[2] = (meta[0] << 16) | (unsigned)(tt * 256 + i);
        meta[3] = remaining - r2;
        break;
      }
      r2 += c;
    }
  }
}

// --------------------------- D: keep flags ---------------------------------
__global__ __launch_bounds__(64) void k_keep(const float* __restrict__ diffs,
                                             const unsigned* __restrict__ meta,
                                             unsigned char* __restrict__ keep) {
  int lane = threadIdx.x;
  unsigned Kstar = meta[2], need = meta[3];
  unsigned base = 0;
  float v[4], nv[4];
#pragma unroll
  for (int q = 0; q < 4; ++q) nv[q] = diffs[q * 64 + lane];
  for (int it = 0; it < 257; ++it) {
#pragma unroll
    for (int q = 0; q < 4; ++q) v[q] = nv[q];
    if (it < 256) {
      int nb = (it + 1) * 256;
#pragma unroll
      for (int q = 0; q < 4; ++q) {
        int idx = nb + q * 64 + lane;
        nv[q] = (idx < NPOS) ? diffs[idx] : 0.f;
      }
    }
#pragma unroll
    for (int q = 0; q < 4; ++q) {
      int p = it * 256 + q * 64 + lane;
      bool valid = p < NPOS;
      unsigned key = valid ? __float_as_uint(v[q]) : 0u;
      bool eq = valid && (key == Kstar);
      unsigned long long m = __ballot(eq);
      unsigned rank = base + (unsigned)__popcll(m & ((1ull << lane) - 1ull));
      bool k = valid && ((key > Kstar) || (eq && rank < need) || ((p & 1023) == 0));
      if (valid) keep[p] = (unsigned char)k;
      base += (unsigned)__popcll(m);
    }
  }
}

// --------------------------- E: per-batch segments -------------------------
__global__ __launch_bounds__(1024) void k_segment(const unsigned char* __restrict__ keep,
                                                  int* __restrict__ segid,
                                                  int* __restrict__ bnd,
                                                  int* __restrict__ nseg) {
  __shared__ int s[1024];
  int b = blockIdx.x, t = threadIdx.x;
  int f = (t >= 1) ? (int)keep[b * 1024 + t] : 0;
  s[t] = f;
  __syncthreads();
  for (int off = 1; off < 1024; off <<= 1) {
    int v = s[t];
    int add = (t >= off) ? s[t - off] : 0;
    __syncthreads();
    s[t] = v + add;
    __syncthreads();
  }
  int sc = s[t];
  segid[b * 1024 + t] = sc;
  if (f) bnd[b * 1026 + sc] = t;
  if (t == 0) bnd[b * 1026] = 0;
  if (t == 1023) {
    int m = sc + 1;
    nseg[b] = m;
    bnd[b * 1026 + m] = 1024;
  }
}

__global__ __launch_bounds__(64) void k_prefix(const int* __restrict__ nseg,
                                               int* __restrict__ pref) {
  int lane = threadIdx.x;
  int s = nseg[lane];
  for (int off = 1; off < 64; off <<= 1) {
    int u = __shfl_up(s, off);
    if (lane >= off) s += u;
  }
  pref[lane + 1] = s;
  if (lane == 0) pref[0] = 0;
}

// --------------------------- G: segment means ------------------------------
__global__ __launch_bounds__(256) void k_pool(const float* __restrict__ x,
                                              const int* __restrict__ bnd,
                                              const int* __restrict__ nseg,
                                              const int* __restrict__ pref,
                                              float* __restrict__ comp) {
  int d = threadIdx.x;
  for (int s = 0; s < 32; ++s) {
    int sid = blockIdx.x * 32 + s;
    int b = sid >> 10, li = sid & 1023;
    if (li >= nseg[b]) continue;
    int s0 = bnd[b * 1026 + li], e0 = bnd[b * 1026 + li + 1];
    float acc = 0.f;
    for (int t = s0; t < e0; ++t) acc += x[((size_t)b * 1024 + t) * 256 + d];
    comp[((size_t)pref[b] + li) * 256 + d] = acc / (float)(e0 - s0);
  }
}

// --------------------------- H: gi GEMM (fp32) -----------------------------
__global__ __launch_bounds__(256) void k_gi(const float* __restrict__ comp,
                                            const float* __restrict__ Wih,
                                            const float* __restrict__ bih,
                                            const float* __restrict__ bhh,
                                            const int* __restrict__ pref,
                                            float* __restrict__ gi) {
  int total = pref[64];
  int r0 = blockIdx.x * 64;
  if (r0 >= total) return;
  int c0 = blockIdx.y * 128;
  __shared__ float As[64][64];
  __shared__ float Bs[64 * 132];
  int tid = threadIdx.x;
  int rg = tid >> 5, cl = tid & 31;
  float acc[8][4];
#pragma unroll
  for (int i = 0; i < 8; ++i)
#pragma unroll
    for (int q = 0; q < 4; ++q) acc[i][q] = 0.f;

  for (int k0 = 0; k0 < 256; k0 += 64) {
#pragma unroll
    for (int i = 0; i < 4; ++i) {
      int idx = tid + i * 256;
      int row = idx >> 4, kq = idx & 15;
      int rr = r0 + row;
      float4 v;
      if (rr < total) v = *reinterpret_cast<const float4*>(comp + (size_t)rr * 256 + k0 + kq * 4);
      else { v.x = 0.f; v.y = 0.f; v.z = 0.f; v.w = 0.f; }
      *reinterpret_cast<float4*>(&As[row][kq * 4]) = v;
    }
#pragma unroll
    for (int i = 0; i < 8; ++i) {
      int idx = tid + i * 256;
      int row = idx >> 4, kq = idx & 15;
      float4 v = *reinterpret_cast<const float4*>(Wih + (size_t)(c0 + row) * 256 + k0 + kq * 4);
      Bs[(kq * 4 + 0) * 132 + row] = v.x;
      Bs[(kq * 4 + 1) * 132 + row] = v.y;
      Bs[(kq * 4 + 2) * 132 + row] = v.z;
      Bs[(kq * 4 + 3) * 132 + row] = v.w;
    }
    __syncthreads();
#pragma unroll 4
    for (int k = 0; k < 64; ++k) {
      float a[8], bv[4];
#pragma unroll
      for (int i = 0; i < 8; ++i) a[i] = As[rg * 8 + i][k];
#pragma unroll
      for (int q = 0; q < 4; ++q) bv[q] = Bs[k * 132 + cl + 32 * q];
#pragma unroll
      for (int i = 0; i < 8; ++i)
#pragma unroll
        for (int q = 0; q < 4; ++q) acc[i][q] += a[i] * bv[q];
    }
    __syncthreads();
  }
#pragma unroll
  for (int q = 0; q < 4; ++q) {
    int c = c0 + cl + 32 * q;
    float bias = bih[c] + (c < 512 ? bhh[c] : 0.f);
#pragma unroll
    for (int i = 0; i < 8; ++i) {
      int rr = r0 + rg * 8 + i;
      if (rr < total) gi[(size_t)rr * 768 + c] = acc[i][q] + bias;
    }
  }
}

// --------------------------- I: GRU ----------------------------------------
// 64 blocks x 512 threads (8 waves, 2/SIMD -> VGPR cap 256). Thread
// (pr = t&255, half = t>>8) owns the three gate rows {pr, 256+pr, 512+pr}
// restricted to k-half `half`: 3 x 64 f16x2 = 192 weight VGPRs, register-
// resident (the previous 768-thr/170-cap version spilled: VGPR=84, +19MB
// scratch writes). h (f16) read as wave-uniform ds_read_b128. Partials via
// LDS float2. Raw s_barrier sync (no vmcnt drain) so gout stores + next-step
// gi prefetch stay in flight.
__global__ __launch_bounds__(512, 2) void k_gru(const float* __restrict__ gi,
                                                const float* __restrict__ Whh,
                                                const float* __restrict__ bhh,
                                                const int* __restrict__ nseg,
                                                const int* __restrict__ pref,
                                                float* __restrict__ gout) {
  const int b = blockIdx.x;
  const int t = threadIdx.x;
  const int m = nseg[b];
  const size_t base = (size_t)pref[b];
  const int half = t >> 8;                 // wave-uniform (waves 0-3 / 4-7)
  const int pr = t & 255;
  const int k0 = half * 128;

  f16x2 wr[64], wz[64], wn[64];
#pragma unroll
  for (int i = 0; i < 32; ++i) {
    float4 v = *(const float4*)(Whh + (size_t)pr * 256 + k0 + i * 4);
    f16x2 ra; ra.x = (_Float16)v.x; ra.y = (_Float16)v.y; wr[2 * i] = ra;
    f16x2 rb; rb.x = (_Float16)v.z; rb.y = (_Float16)v.w; wr[2 * i + 1] = rb;
    float4 u = *(const float4*)(Whh + (size_t)(256 + pr) * 256 + k0 + i * 4);
    f16x2 za; za.x = (_Float16)u.x; za.y = (_Float16)u.y; wz[2 * i] = za;
    f16x2 zb; zb.x = (_Float16)u.z; zb.y = (_Float16)u.w; wz[2 * i + 1] = zb;
    float4 q = *(const float4*)(Whh + (size_t)(512 + pr) * 256 + k0 + i * 4);
    f16x2 na; na.x = (_Float16)q.x; na.y = (_Float16)q.y; wn[2 * i] = na;
    f16x2 nb; nb.x = (_Float16)q.z; nb.y = (_Float16)q.w; wn[2 * i + 1] = nb;
  }

  __shared__ f16x8 hbuf8[32];     // h as f16 (256 vals); [half*16+i] uniform
  __shared__ float2 pp2[768];     // per-row {half0, half1} partials

  float bn = (t < 256) ? bhh[512 + t] : 0.f;
  float hreg = 0.f;               // finish thread t<256 owns h[t] in f32
  if (t < 32) {
    f16x8 z = (f16x8)(_Float16)0.f;
    hbuf8[t] = z;
  }
  __syncthreads();

  float cr = 0.f, cz = 0.f, cn = 0.f;
  if (t < 256) {
    const float* g0 = gi + base * 768;
    cr = g0[t]; cz = g0[256 + t]; cn = g0[512 + t];
  }

  for (int l = 0; l < m; ++l) {
    float nr = 0.f, nz = 0.f, nn = 0.f;
    if (t < 256 && l + 1 < m) {            // prefetch next step's gi
      const float* g1 = gi + (base + l + 1) * 768;
      nr = g1[t]; nz = g1[256 + t]; nn = g1[512 + t];
    }
    float ar0 = 0.f, ar1 = 0.f, az0 = 0.f, az1 = 0.f, an0 = 0.f, an1 = 0.f;
#pragma unroll
    for (int i = 0; i < 16; ++i) {
      f16x8 hv = hbuf8[half * 16 + i];     // uniform ds_read_b128
      f16x2 p0; p0.x = hv[0]; p0.y = hv[1];
      f16x2 p1; p1.x = hv[2]; p1.y = hv[3];
      f16x2 p2; p2.x = hv[4]; p2.y = hv[5];
      f16x2 p3; p3.x = hv[6]; p3.y = hv[7];
      ar0 = fdot2f(wr[4 * i + 0], p0, ar0);
      ar1 = fdot2f(wr[4 * i + 1], p1, ar1);
      ar0 = fdot2f(wr[4 * i + 2], p2, ar0);
      ar1 = fdot2f(wr[4 * i + 3], p3, ar1);
      az0 = fdot2f(wz[4 * i + 0], p0, az0);
      az1 = fdot2f(wz[4 * i + 1], p1, az1);
      az0 = fdot2f(wz[4 * i + 2], p2, az0);
      az1 = fdot2f(wz[4 * i + 3], p3, az1);
      an0 = fdot2f(wn[4 * i + 0], p0, an0);
      an1 = fdot2f(wn[4 * i + 1], p1, an1);
      an0 = fdot2f(wn[4 * i + 2], p2, an0);
      an1 = fdot2f(wn[4 * i + 3], p3, an1);
    }
    float* ppf = (float*)pp2;
    ppf[pr * 2 + half] = ar0 + ar1;
    ppf[(256 + pr) * 2 + half] = az0 + az1;
    ppf[(512 + pr) * 2 + half] = an0 + an1;
    asm volatile("s_waitcnt lgkmcnt(0)" ::: "memory");
    __builtin_amdgcn_sched_barrier(0);
    __builtin_amdgcn_s_barrier();
    __builtin_amdgcn_sched_barrier(0);
    if (t < 256) {
      float2 qr = pp2[t];
      float2 qz = pp2[256 + t];
      float2 qn = pp2[512 + t];
      float sr = qr.x + qr.y;
      float sz = qz.x + qz.y;
      float sn = qn.x + qn.y + bn;
      float r = 1.f / (1.f + __expf(-(cr + sr)));
      float z = 1.f / (1.f + __expf(-(cz + sz)));
      float arg = cn + r * sn;
      float n = 2.f / (1.f + __expf(-2.f * arg)) - 1.f;   // tanh
      float hnew = (1.f - z) * n + z * hreg;
      hreg = hnew;
      ((_Float16*)hbuf8)[t] = (_Float16)hnew;
      gout[(base + l) * 256 + t] = hnew;
    }
    cr = nr; cz = nz; cn = nn;
    asm volatile("s_waitcnt lgkmcnt(0)" ::: "memory");
    __builtin_amdgcn_sched_barrier(0);
    __builtin_amdgcn_s_barrier();
    __builtin_amdgcn_sched_barrier(0);
  }
}

// --------------------------- J: scatter ------------------------------------
__global__ __launch_bounds__(256) void k_scatter(const float* __restrict__ gout,
                                                 const int* __restrict__ segid,
                                                 const int* __restrict__ pref,
                                                 float* __restrict__ out) {
  int d = threadIdx.x;
  for (int rr = 0; rr < 32; ++rr) {
    int row = blockIdx.x * 32 + rr;
    int b = row >> 10;
    int l = segid[row];
    out[(size_t)row * 256 + d] = gout[((size_t)pref[b] + l) * 256 + d];
  }
}

// ---------------------------------------------------------------------------
extern "C" void kernel_launch(void* const* d_in, const int* in_sizes, int n_in,
                              void* d_out, int out_size, void* d_ws, size_t ws_size,
                              hipStream_t stream) {
  const float* x   = (const float*)d_in[0];
  const float* Wih = (const float*)d_in[1];
  const float* Whh = (const float*)d_in[2];
  const float* bih = (const float*)d_in[3];
  const float* bhh = (const float*)d_in[4];
  float* out = (float*)d_out;
  char* w = (char*)d_ws;

  const size_t o_cs1   = 0;
  const size_t o_cs2   = 67110912;
  const size_t o_diffs = 134221824;
  const size_t o_h1    = 134484224;
  const size_t o_h2    = 134746368;
  const size_t o_meta  = 135008512;
  const size_t o_keep  = 135008768;
  const size_t o_segid = 135074560;
  const size_t o_bnd   = 135336704;
  const size_t o_nseg  = 135599360;
  const size_t o_pref  = 135599616;
  const size_t o_gi    = 135600128;
  const size_t NEED    = 236460032;
  if (ws_size < NEED) return;

  float* cs1 = (float*)(w + o_cs1);
  float* cs2 = (float*)(w + o_cs2);
  float* diffs = (float*)(w + o_diffs);
  unsigned* h1 = (unsigned*)(w + o_h1);
  unsigned* h2 = (unsigned*)(w + o_h2);
  unsigned* meta = (unsigned*)(w + o_meta);
  unsigned char* keep = (unsigned char*)(w + o_keep);
  int* segid = (int*)(w + o_segid);
  int* bnd = (int*)(w + o_bnd);
  int* nseg = (int*)(w + o_nseg);
  int* pref = (int*)(w + o_pref);
  float* gi = (float*)(w + o_gi);
  float* carr = (float*)(w + o_gi);   // 524,288 B; dead before k_gi writes gi
  float* comp = cs1;                  // reuse (cs1 dead after k_diffs)
  float* gout = cs2;                  // reuse
  float* sink = (float*)(w + o_meta + 192);

  hipMemsetAsync(h1, 0, 262144, stream);
  hipMemsetAsync(h2, 0, 262144, stream);

  k_warm   <<<dim3(16384),  dim3(256),  0, stream>>>((const float4*)x, sink);
  k_carry  <<<dim3(8),      dim3(256),  0, stream>>>(x, carr);
  k_spread <<<dim3(512),    dim3(256),  0, stream>>>(x, carr, cs1, cs2);
  k_diffs  <<<dim3(1025),   dim3(64),   0, stream>>>(cs1, cs2, diffs);
  k_hist1  <<<dim3(257),    dim3(256),  0, stream>>>(diffs, h1);
  k_sel_hi <<<dim3(1),      dim3(256),  0, stream>>>(h1, meta);
  k_hist2  <<<dim3(257),    dim3(256),  0, stream>>>(diffs, meta, h2);
  k_sel_lo <<<dim3(1),      dim3(256),  0, stream>>>(h2, meta);
  k_keep   <<<dim3(1),      dim3(64),   0, stream>>>(diffs, meta, keep);
  k_segment<<<dim3(64),     dim3(1024), 0, stream>>>(keep, segid, bnd, nseg);
  k_prefix <<<dim3(1),      dim3(64),   0, stream>>>(nseg, pref);
  k_pool   <<<dim3(2048),   dim3(256),  0, stream>>>(x, bnd, nseg, pref, comp);
  k_gi     <<<dim3(513, 6), dim3(256),  0, stream>>>(comp, Wih, bih, bhh, pref, gi);
  k_gru    <<<dim3(64),     dim3(512),  0, stream>>>(gi, Whh, bhh, nseg, pref, gout);
  k_scatter<<<dim3(2048),   dim3(256),  0, stream>>>(gout, segid, pref, out);
}